// Round 2
// baseline (430.842 us; speedup 1.0000x reference)
//
#include <hip/hip_runtime.h>
#include <hip/hip_bf16.h>
#include <cstddef>

typedef short short8 __attribute__((ext_vector_type(8)));
typedef float floatx4 __attribute__((ext_vector_type(4)));

__device__ __forceinline__ unsigned int bf16_rne(float x) {
    unsigned int u = __float_as_uint(x);
    return (u + 0x7fffu + ((u >> 16) & 1u)) >> 16;
}

// split fp32x4 -> bf16 hi pack + bf16 lo (residual) pack
__device__ __forceinline__ void split4(const floatx4 v,
                                       unsigned long long& hp,
                                       unsigned long long& lp) {
    unsigned int h[4], l[4];
    #pragma unroll
    for (int j = 0; j < 4; ++j) {
        h[j] = bf16_rne(v[j]);
        float hf = __uint_as_float(h[j] << 16);
        l[j] = bf16_rne(v[j] - hf);
    }
    hp = (unsigned long long)(h[0] | (h[1] << 16)) |
         ((unsigned long long)(h[2] | (h[3] << 16)) << 32);
    lp = (unsigned long long)(l[0] | (l[1] << 16)) |
         ((unsigned long long)(l[2] | (l[3] << 16)) << 32);
}

// ---------------------------------------------------------------------------
// Generic NT GEMM with bf16x3 error compensation:
//   C[M][N] = alpha * A[M][K] * Bt[N][K]^T (+ bias[n])
// A, Bt fp32 row-major; split into bf16 hi+lo while staging into LDS.
// acc += Al*Bh + Ah*Bl + Ah*Bh  -> ~fp32-grade product accuracy.
// Block = 256 threads = 4 waves in a 2x2 grid, each wave owns (BM/2)x(BN/2).
// If STORE_T, C is written transposed: C[n*ldc + m] (float4 along m).
// ---------------------------------------------------------------------------
template<int BM, int BN, bool STORE_T, bool HAS_BIAS>
__global__ __launch_bounds__(256, 2)
void gemm_nt(const float* __restrict__ A, const float* __restrict__ Bt,
             float* __restrict__ C, const float* __restrict__ bias,
             int K, long sA, long sB, long sC, int ldc, float alpha)
{
    constexpr int LDS_STRIDE = 40;   // 32 + 8 pad -> 80B rows, 2-way bank alias (free)
    __shared__ unsigned short Ah[BM][LDS_STRIDE];
    __shared__ unsigned short Al[BM][LDS_STRIDE];
    __shared__ unsigned short Bh[BN][LDS_STRIDE];
    __shared__ unsigned short Bl[BN][LDS_STRIDE];

    const int b = blockIdx.z;
    A  += (long)b * sA;
    Bt += (long)b * sB;
    C  += (long)b * sC;
    const int bm0 = blockIdx.y * BM;
    const int bn0 = blockIdx.x * BN;

    const int tid  = threadIdx.x;
    const int lane = tid & 63;
    const int wid  = tid >> 6;
    const int wr   = wid >> 1, wc = wid & 1;
    constexpr int WM = BM / 2, WN = BN / 2;
    constexpr int FM = WM / 16, FN = WN / 16;

    floatx4 acc[FM][FN] = {};

    const int l15  = lane & 15;
    const int koff = (lane >> 4) * 8;    // 8 contiguous bf16 per lane group

    for (int k0 = 0; k0 < K; k0 += 32) {
        // ---- stage A tile (BM x 32) fp32 -> bf16 hi/lo ----
        #pragma unroll
        for (int i = 0; i < (BM * 32) / 1024; ++i) {
            int flat = i * 1024 + tid * 4;
            int r = flat >> 5, c = flat & 31;
            floatx4 v = *(const floatx4*)(A + (long)(bm0 + r) * K + (k0 + c));
            unsigned long long hp, lp;
            split4(v, hp, lp);
            *(unsigned long long*)&Ah[r][c] = hp;
            *(unsigned long long*)&Al[r][c] = lp;
        }
        // ---- stage Bt tile (BN x 32) ----
        #pragma unroll
        for (int i = 0; i < (BN * 32) / 1024; ++i) {
            int flat = i * 1024 + tid * 4;
            int r = flat >> 5, c = flat & 31;
            floatx4 v = *(const floatx4*)(Bt + (long)(bn0 + r) * K + (k0 + c));
            unsigned long long hp, lp;
            split4(v, hp, lp);
            *(unsigned long long*)&Bh[r][c] = hp;
            *(unsigned long long*)&Bl[r][c] = lp;
        }
        __syncthreads();

        short8 ah[FM], al[FM], bh[FN], bl[FN];
        #pragma unroll
        for (int mi = 0; mi < FM; ++mi) {
            ah[mi] = *(const short8*)&Ah[wr * WM + mi * 16 + l15][koff];
            al[mi] = *(const short8*)&Al[wr * WM + mi * 16 + l15][koff];
        }
        #pragma unroll
        for (int ni = 0; ni < FN; ++ni) {
            bh[ni] = *(const short8*)&Bh[wc * WN + ni * 16 + l15][koff];
            bl[ni] = *(const short8*)&Bl[wc * WN + ni * 16 + l15][koff];
        }

        #pragma unroll
        for (int mi = 0; mi < FM; ++mi)
            #pragma unroll
            for (int ni = 0; ni < FN; ++ni) {
                acc[mi][ni] = __builtin_amdgcn_mfma_f32_16x16x32_bf16(
                    al[mi], bh[ni], acc[mi][ni], 0, 0, 0);
                acc[mi][ni] = __builtin_amdgcn_mfma_f32_16x16x32_bf16(
                    ah[mi], bl[ni], acc[mi][ni], 0, 0, 0);
                acc[mi][ni] = __builtin_amdgcn_mfma_f32_16x16x32_bf16(
                    ah[mi], bh[ni], acc[mi][ni], 0, 0, 0);
            }
        __syncthreads();
    }

    // ---- epilogue: C row = (lane>>4)*4 + reg, col = lane&15 ----
    const int rq = (lane >> 4) * 4;
    #pragma unroll
    for (int mi = 0; mi < FM; ++mi) {
        #pragma unroll
        for (int ni = 0; ni < FN; ++ni) {
            int gm = bm0 + wr * WM + mi * 16 + rq;
            int gn = bn0 + wc * WN + ni * 16 + l15;
            float bv = 0.f;
            if (HAS_BIAS) bv = bias[gn];
            if (STORE_T) {
                floatx4 o;
                #pragma unroll
                for (int j = 0; j < 4; ++j) o[j] = acc[mi][ni][j] * alpha + bv;
                *(floatx4*)(C + (long)gn * ldc + gm) = o;
            } else {
                #pragma unroll
                for (int j = 0; j < 4; ++j)
                    C[(long)(gm + j) * ldc + gn] = acc[mi][ni][j] * alpha + bv;
            }
        }
    }
}

// ---------------------------------------------------------------------------
// Row softmax in place: grid.x = nrows, 256 threads, COLS/256 elems per thread
// ---------------------------------------------------------------------------
template<int COLS>
__global__ __launch_bounds__(256)
void softmax_rows(float* __restrict__ data)
{
    constexpr int NPT = COLS / 256;
    float* p = data + (long)blockIdx.x * COLS;
    const int t = threadIdx.x;
    const int wid = t >> 6;
    __shared__ float red[4];

    float v[NPT];
    float m = -1e30f;
    #pragma unroll
    for (int i = 0; i < NPT; ++i) {
        v[i] = p[t + i * 256];
        m = fmaxf(m, v[i]);
    }
    #pragma unroll
    for (int off = 32; off; off >>= 1) m = fmaxf(m, __shfl_xor(m, off));
    if ((t & 63) == 0) red[wid] = m;
    __syncthreads();
    m = fmaxf(fmaxf(red[0], red[1]), fmaxf(red[2], red[3]));

    float s = 0.f;
    #pragma unroll
    for (int i = 0; i < NPT; ++i) {
        v[i] = __expf(v[i] - m);
        s += v[i];
    }
    #pragma unroll
    for (int off = 32; off; off >>= 1) s += __shfl_xor(s, off);
    __syncthreads();
    if ((t & 63) == 0) red[wid] = s;
    __syncthreads();
    s = red[0] + red[1] + red[2] + red[3];
    float inv = 1.f / s;
    #pragma unroll
    for (int i = 0; i < NPT; ++i) p[t + i * 256] = v[i] * inv;
}

// ---------------------------------------------------------------------------
// 32x32 tiled transpose: in[R][C] -> out[C][R]; block (32,8), grid (C/32, R/32)
// ---------------------------------------------------------------------------
__global__ __launch_bounds__(256)
void transpose_k(const float* __restrict__ in, float* __restrict__ out, int R, int C)
{
    __shared__ float tile[32][33];
    const int tc = blockIdx.x * 32, tr = blockIdx.y * 32;
    const int x = threadIdx.x, y = threadIdx.y;
    #pragma unroll
    for (int i = 0; i < 32; i += 8)
        tile[y + i][x] = in[(long)(tr + y + i) * C + tc + x];
    __syncthreads();
    #pragma unroll
    for (int i = 0; i < 32; i += 8)
        out[(long)(tc + y + i) * R + tr + x] = tile[x][y + i];
}

extern "C" void kernel_launch(void* const* d_in, const int* in_sizes, int n_in,
                              void* d_out, int out_size, void* d_ws, size_t ws_size,
                              hipStream_t stream)
{
    (void)in_sizes; (void)n_in; (void)out_size; (void)ws_size;
    const float* x_T    = (const float*)d_in[0];
    const float* x_S    = (const float*)d_in[1];
    const float* Wq_T   = (const float*)d_in[2];
    const float* Wk_T   = (const float*)d_in[3];
    const float* Wv_T   = (const float*)d_in[4];
    const float* Wq_S   = (const float*)d_in[5];
    const float* Wk_S   = (const float*)d_in[6];
    const float* Wout_T = (const float*)d_in[7];
    const float* bout_T = (const float*)d_in[8];
    const float* bias_T = (const float*)d_in[9];
    const float* bias_S = (const float*)d_in[10];
    float* out = (float*)d_out;

    constexpr int B = 16, T = 1024, N = 512, DKT = 64, DKS = 128;

    float* ws = (float*)d_ws;
    size_t off = 0;
    auto alloc = [&](size_t n) { float* p = ws + off; off += n; return p; };
    float* wqt_t  = alloc((size_t)DKT * N);     // [64][512]
    float* wkt_t  = alloc((size_t)DKT * N);
    float* wvt_t  = alloc((size_t)N * N);       // [512][512]
    float* wqs_t  = alloc((size_t)DKS * T);     // [128][1024]
    float* wks_t  = alloc((size_t)DKS * T);
    float* wout_t = alloc((size_t)N * N);
    float* qT     = alloc((size_t)B * T * DKT); // reused as qS ([B*N][DKS], same size)
    float* kT     = alloc((size_t)B * T * DKT); // reused as kS
    float* vTt    = alloc((size_t)B * N * T);   // reused as attnS (smaller)
    float* attnT  = alloc((size_t)B * T * T);   // reused as out2 (half)
    float* outT   = alloc((size_t)B * T * N);
    float* qS    = qT;
    float* kS    = kT;
    float* attnS = vTt;
    float* out2  = attnT;
    // peak ws: ~146 MB

    dim3 tb(32, 8);
    transpose_k<<<dim3(DKT / 32, N / 32), tb, 0, stream>>>(Wq_T, wqt_t, N, DKT);
    transpose_k<<<dim3(DKT / 32, N / 32), tb, 0, stream>>>(Wk_T, wkt_t, N, DKT);
    transpose_k<<<dim3(N / 32, N / 32), tb, 0, stream>>>(Wv_T, wvt_t, N, N);
    transpose_k<<<dim3(DKS / 32, T / 32), tb, 0, stream>>>(Wq_S, wqs_t, T, DKS);
    transpose_k<<<dim3(DKS / 32, T / 32), tb, 0, stream>>>(Wk_S, wks_t, T, DKS);
    transpose_k<<<dim3(N / 32, N / 32), tb, 0, stream>>>(Wout_T, wout_t, N, N);

    const float scale_T = 0.125f;                 // 64^-0.5
    const float scale_S = 0.088388347648318447f;  // 128^-0.5

    // 1. qT = x_T @ Wq_T * scale_T + bias_T    [16384 x 64], K=512
    gemm_nt<128, 64, false, true><<<dim3(1, (B * T) / 128, 1), 256, 0, stream>>>(
        x_T, wqt_t, qT, bias_T, 512, 0, 0, 0, DKT, scale_T);
    // 2. kT = x_T @ Wk_T                        [16384 x 64], K=512
    gemm_nt<128, 64, false, false><<<dim3(1, (B * T) / 128, 1), 256, 0, stream>>>(
        x_T, wkt_t, kT, nullptr, 512, 0, 0, 0, DKT, 1.0f);
    // 3. vTt_b = Wv^T @ x_T_b^T                 [512 x 1024] per b, K=512
    gemm_nt<128, 128, false, false><<<dim3(T / 128, N / 128, B), 256, 0, stream>>>(
        wvt_t, x_T, vTt, nullptr, 512, 0, (long)T * N, (long)N * T, T, 1.0f);
    // 4. logits_T = qT_b @ kT_b^T               [1024 x 1024] per b, K=64
    gemm_nt<128, 128, false, false><<<dim3(T / 128, T / 128, B), 256, 0, stream>>>(
        qT, kT, attnT, nullptr, DKT, (long)T * DKT, (long)T * DKT, (long)T * T, T, 1.0f);
    // 5. softmax rows of attnT
    softmax_rows<1024><<<B * T, 256, 0, stream>>>(attnT);
    // 6. outT = attnT_b @ vT_b = attnT_b @ vTt_b^T   [1024 x 512] per b, K=1024
    gemm_nt<128, 128, false, false><<<dim3(N / 128, T / 128, B), 256, 0, stream>>>(
        attnT, vTt, outT, nullptr, T, (long)T * T, (long)N * T, (long)T * N, N, 1.0f);
    // 7. qS = x_S @ Wq_S * scale_S + bias_S     [8192 x 128], K=1024
    gemm_nt<128, 128, false, true><<<dim3(1, (B * N) / 128, 1), 256, 0, stream>>>(
        x_S, wqs_t, qS, bias_S, T, 0, 0, 0, DKS, scale_S);
    // 8. kS = x_S @ Wk_S                        [8192 x 128], K=1024
    gemm_nt<128, 128, false, false><<<dim3(1, (B * N) / 128, 1), 256, 0, stream>>>(
        x_S, wks_t, kS, nullptr, T, 0, 0, 0, DKS, 1.0f);
    // 9. logits_S = qS_b @ kS_b^T               [512 x 512] per b, K=128
    gemm_nt<128, 128, false, false><<<dim3(N / 128, N / 128, B), 256, 0, stream>>>(
        qS, kS, attnS, nullptr, DKS, (long)N * DKS, (long)N * DKS, (long)N * N, N, 1.0f);
    // 10. softmax rows of attnS
    softmax_rows<512><<<B * N, 256, 0, stream>>>(attnS);
    // 11. out2 = outT_b @ attnS_b^T             [1024 x 512] per b, K=512
    gemm_nt<128, 128, false, false><<<dim3(N / 128, T / 128, B), 256, 0, stream>>>(
        outT, attnS, out2, nullptr, N, (long)T * N, (long)N * N, (long)T * N, N, 1.0f);
    // 12. out[b,n,t] = (out2_b @ Wout + bout)^T  [512 x 1024] per b via STORE_T, K=512
    gemm_nt<128, 128, true, true><<<dim3(N / 128, T / 128, B), 256, 0, stream>>>(
        out2, wout_t, out, bout_T, N, (long)T * N, 0, (long)N * T, T, 1.0f);
}

// Round 3
// 330.451 us; speedup vs baseline: 1.3038x; 1.3038x over previous
//
#include <hip/hip_runtime.h>
#include <cstddef>

typedef short short8 __attribute__((ext_vector_type(8)));
typedef unsigned short ushortx8 __attribute__((ext_vector_type(8)));
typedef float floatx4 __attribute__((ext_vector_type(4)));

__device__ __forceinline__ unsigned int bf16_rne(float x) {
    unsigned int u = __float_as_uint(x);
    return (u + 0x7fffu + ((u >> 16) & 1u)) >> 16;
}

// fp32x4 -> bf16 hi pack + bf16 lo (residual) pack
__device__ __forceinline__ void split4(const floatx4 v,
                                       unsigned long long& hp,
                                       unsigned long long& lp) {
    unsigned int h[4], l[4];
    #pragma unroll
    for (int j = 0; j < 4; ++j) {
        h[j] = bf16_rne(v[j]);
        float hf = __uint_as_float(h[j] << 16);
        l[j] = bf16_rne(v[j] - hf);
    }
    hp = (unsigned long long)(h[0] | (h[1] << 16)) |
         ((unsigned long long)(h[2] | (h[3] << 16)) << 32);
    lp = (unsigned long long)(l[0] | (l[1] << 16)) |
         ((unsigned long long)(l[2] | (l[3] << 16)) << 32);
}

__device__ __forceinline__ unsigned long long pack_hi4(const floatx4 v) {
    unsigned int h0 = bf16_rne(v[0]), h1 = bf16_rne(v[1]);
    unsigned int h2 = bf16_rne(v[2]), h3 = bf16_rne(v[3]);
    return (unsigned long long)(h0 | (h1 << 16)) |
           ((unsigned long long)(h2 | (h3 << 16)) << 32);
}

// ---------------------------------------------------------------------------
// NT GEMM, operands either fp32 (split to bf16 during LDS staging) or
// pre-split bf16 hi/lo planes.
//   AMODE/BMODE: 0 = fp32 src, hi only; 1 = fp32 src, hi+lo;
//                2 = bf16 planes, hi only; 3 = bf16 planes, hi+lo
//   MFMA passes: Ah*Bh (+ Al*Bh if A has lo) (+ Ah*Bl if B has lo)
//   OUTMODE: 0 = fp32 row-major; 1 = fp32 transposed (float4 along m);
//            2 = bf16 hi/lo planes
//   Epilogue: for col gn < nsplit: val = acc*alpha + bias[gn]; else val = acc.
// Block = 256 threads = 4 waves (2x2), wave owns (BM/2)x(BN/2).
// ---------------------------------------------------------------------------
template<int BM, int BN, int AMODE, int BMODE, int OUTMODE, bool HASBIAS>
__global__ __launch_bounds__(256, 2)
void gemm_nt(const void* __restrict__ Ah_, const void* __restrict__ Al_,
             const void* __restrict__ Bh_, const void* __restrict__ Bl_,
             void* __restrict__ C_, void* __restrict__ Cl_,
             const float* __restrict__ bias,
             int K, int lda, int ldb, int ldc,
             long sA, long sB, long sC, float alpha, int nsplit)
{
    constexpr bool ALO = (AMODE == 1 || AMODE == 3);
    constexpr bool BLO = (BMODE == 1 || BMODE == 3);
    constexpr int LS = 40;   // 32 + 8 pad halves -> 80B rows, 2-way bank alias (free)
    __shared__ unsigned short Ash[BM][LS];
    __shared__ unsigned short Als[ALO ? BM : 1][LS];
    __shared__ unsigned short Bsh[BN][LS];
    __shared__ unsigned short Bls[BLO ? BN : 1][LS];

    const int b   = blockIdx.z;
    const int bm0 = blockIdx.y * BM;
    const int bn0 = blockIdx.x * BN;
    const int tid  = threadIdx.x;
    const int lane = tid & 63;
    const int wid  = tid >> 6;
    const int wr = wid >> 1, wc = wid & 1;
    constexpr int WM = BM / 2, WN = BN / 2;
    constexpr int FM = WM / 16, FN = WN / 16;
    floatx4 acc[FM][FN] = {};
    const int l15  = lane & 15;
    const int koff = (lane >> 4) * 8;

    for (int k0 = 0; k0 < K; k0 += 32) {
        // ---- stage A (BM x 32) ----
        if (AMODE <= 1) {
            const float* A = (const float*)Ah_ + (long)b * sA;
            #pragma unroll
            for (int i = 0; i < (BM * 32) / 1024; ++i) {
                int flat = i * 1024 + tid * 4;
                int r = flat >> 5, c = flat & 31;
                floatx4 v = *(const floatx4*)(A + (long)(bm0 + r) * lda + k0 + c);
                if (AMODE == 1) {
                    unsigned long long hp, lp; split4(v, hp, lp);
                    *(unsigned long long*)&Ash[r][c] = hp;
                    *(unsigned long long*)&Als[r][c] = lp;
                } else {
                    *(unsigned long long*)&Ash[r][c] = pack_hi4(v);
                }
            }
        } else {
            const unsigned short* A = (const unsigned short*)Ah_ + (long)b * sA;
            const unsigned short* Al = (const unsigned short*)Al_ + (long)b * sA;
            #pragma unroll
            for (int i = 0; i < (BM * 32) / 2048; ++i) {
                int flat = i * 2048 + tid * 8;
                int r = flat >> 5, c = flat & 31;
                *(ushortx8*)&Ash[r][c] = *(const ushortx8*)(A + (long)(bm0 + r) * lda + k0 + c);
                if (AMODE == 3)
                    *(ushortx8*)&Als[r][c] = *(const ushortx8*)(Al + (long)(bm0 + r) * lda + k0 + c);
            }
        }
        // ---- stage B (BN x 32) ----
        if (BMODE <= 1) {
            const float* Bp = (const float*)Bh_ + (long)b * sB;
            #pragma unroll
            for (int i = 0; i < (BN * 32) / 1024; ++i) {
                int flat = i * 1024 + tid * 4;
                int r = flat >> 5, c = flat & 31;
                floatx4 v = *(const floatx4*)(Bp + (long)(bn0 + r) * ldb + k0 + c);
                if (BMODE == 1) {
                    unsigned long long hp, lp; split4(v, hp, lp);
                    *(unsigned long long*)&Bsh[r][c] = hp;
                    *(unsigned long long*)&Bls[r][c] = lp;
                } else {
                    *(unsigned long long*)&Bsh[r][c] = pack_hi4(v);
                }
            }
        } else {
            const unsigned short* Bp = (const unsigned short*)Bh_ + (long)b * sB;
            const unsigned short* Bl = (const unsigned short*)Bl_ + (long)b * sB;
            #pragma unroll
            for (int i = 0; i < (BN * 32) / 2048; ++i) {
                int flat = i * 2048 + tid * 8;
                int r = flat >> 5, c = flat & 31;
                *(ushortx8*)&Bsh[r][c] = *(const ushortx8*)(Bp + (long)(bn0 + r) * ldb + k0 + c);
                if (BMODE == 3)
                    *(ushortx8*)&Bls[r][c] = *(const ushortx8*)(Bl + (long)(bn0 + r) * ldb + k0 + c);
            }
        }
        __syncthreads();

        short8 ah[FM], al[FM], bh[FN], bl[FN];
        #pragma unroll
        for (int mi = 0; mi < FM; ++mi) {
            ah[mi] = *(const short8*)&Ash[wr * WM + mi * 16 + l15][koff];
            if (ALO) al[mi] = *(const short8*)&Als[wr * WM + mi * 16 + l15][koff];
        }
        #pragma unroll
        for (int ni = 0; ni < FN; ++ni) {
            bh[ni] = *(const short8*)&Bsh[wc * WN + ni * 16 + l15][koff];
            if (BLO) bl[ni] = *(const short8*)&Bls[wc * WN + ni * 16 + l15][koff];
        }

        #pragma unroll
        for (int mi = 0; mi < FM; ++mi)
            #pragma unroll
            for (int ni = 0; ni < FN; ++ni) {
                if (ALO)
                    acc[mi][ni] = __builtin_amdgcn_mfma_f32_16x16x32_bf16(
                        al[mi], bh[ni], acc[mi][ni], 0, 0, 0);
                if (BLO)
                    acc[mi][ni] = __builtin_amdgcn_mfma_f32_16x16x32_bf16(
                        ah[mi], bl[ni], acc[mi][ni], 0, 0, 0);
                acc[mi][ni] = __builtin_amdgcn_mfma_f32_16x16x32_bf16(
                    ah[mi], bh[ni], acc[mi][ni], 0, 0, 0);
            }
        __syncthreads();
    }

    // ---- epilogue: C row = (lane>>4)*4 + reg, col = lane&15 ----
    const int rq = (lane >> 4) * 4;
    #pragma unroll
    for (int mi = 0; mi < FM; ++mi) {
        #pragma unroll
        for (int ni = 0; ni < FN; ++ni) {
            int gm = bm0 + wr * WM + mi * 16 + rq;
            int gn = bn0 + wc * WN + ni * 16 + l15;
            float ae = (gn < nsplit) ? alpha : 1.0f;
            float be = 0.f;
            if (HASBIAS) be = (gn < nsplit) ? bias[gn] : 0.0f;
            float vals[4];
            #pragma unroll
            for (int j = 0; j < 4; ++j) vals[j] = acc[mi][ni][j] * ae + be;
            if (OUTMODE == 0) {
                float* C = (float*)C_ + (long)b * sC;
                #pragma unroll
                for (int j = 0; j < 4; ++j) C[(long)(gm + j) * ldc + gn] = vals[j];
            } else if (OUTMODE == 1) {
                float* C = (float*)C_ + (long)b * sC;
                floatx4 o;
                #pragma unroll
                for (int j = 0; j < 4; ++j) o[j] = vals[j];
                *(floatx4*)(C + (long)gn * ldc + gm) = o;
            } else {
                unsigned short* Ch = (unsigned short*)C_ + (long)b * sC;
                unsigned short* Cl = (unsigned short*)Cl_ + (long)b * sC;
                #pragma unroll
                for (int j = 0; j < 4; ++j) {
                    unsigned int h = bf16_rne(vals[j]);
                    float hf = __uint_as_float(h << 16);
                    unsigned int lo = bf16_rne(vals[j] - hf);
                    Ch[(long)(gm + j) * ldc + gn] = (unsigned short)h;
                    Cl[(long)(gm + j) * ldc + gn] = (unsigned short)lo;
                }
            }
        }
    }
}

// ---------------------------------------------------------------------------
// Row softmax in place (fp32): grid.x = nrows, 256 threads
// ---------------------------------------------------------------------------
template<int COLS>
__global__ __launch_bounds__(256)
void softmax_rows(float* __restrict__ data)
{
    constexpr int NPT = COLS / 256;
    float* p = data + (long)blockIdx.x * COLS;
    const int t = threadIdx.x;
    const int wid = t >> 6;
    __shared__ float red[4];

    float v[NPT];
    float m = -1e30f;
    #pragma unroll
    for (int i = 0; i < NPT; ++i) {
        v[i] = p[t + i * 256];
        m = fmaxf(m, v[i]);
    }
    #pragma unroll
    for (int off = 32; off; off >>= 1) m = fmaxf(m, __shfl_xor(m, off));
    if ((t & 63) == 0) red[wid] = m;
    __syncthreads();
    m = fmaxf(fmaxf(red[0], red[1]), fmaxf(red[2], red[3]));

    float s = 0.f;
    #pragma unroll
    for (int i = 0; i < NPT; ++i) {
        v[i] = __expf(v[i] - m);
        s += v[i];
    }
    #pragma unroll
    for (int off = 32; off; off >>= 1) s += __shfl_xor(s, off);
    __syncthreads();
    if ((t & 63) == 0) red[wid] = s;
    __syncthreads();
    s = red[0] + red[1] + red[2] + red[3];
    float inv = 1.f / s;
    #pragma unroll
    for (int i = 0; i < NPT; ++i) p[t + i * 256] = v[i] * inv;
}

// ---------------------------------------------------------------------------
// Transpose + split: in[R][C] fp32 -> outH/outL[(c+rowOff)][r] bf16 planes
// block (32,8), grid (C/32, R/32)
// ---------------------------------------------------------------------------
__global__ __launch_bounds__(256)
void transpose_split(const float* __restrict__ in,
                     unsigned short* __restrict__ outH,
                     unsigned short* __restrict__ outL,
                     int R, int C, int rowOff, int ldo)
{
    __shared__ float tile[32][33];
    const int tc = blockIdx.x * 32, tr = blockIdx.y * 32;
    const int x = threadIdx.x, y = threadIdx.y;
    #pragma unroll
    for (int i = 0; i < 32; i += 8)
        tile[y + i][x] = in[(long)(tr + y + i) * C + tc + x];
    __syncthreads();
    #pragma unroll
    for (int i = 0; i < 32; i += 8) {
        float v = tile[x][y + i];
        unsigned int h = bf16_rne(v);
        float hf = __uint_as_float(h << 16);
        unsigned int lo = bf16_rne(v - hf);
        long idx = (long)(tc + y + i + rowOff) * ldo + tr + x;
        outH[idx] = (unsigned short)h;
        outL[idx] = (unsigned short)lo;
    }
}

extern "C" void kernel_launch(void* const* d_in, const int* in_sizes, int n_in,
                              void* d_out, int out_size, void* d_ws, size_t ws_size,
                              hipStream_t stream)
{
    (void)in_sizes; (void)n_in; (void)out_size; (void)ws_size;
    const float* x_T    = (const float*)d_in[0];
    const float* x_S    = (const float*)d_in[1];
    const float* Wq_T   = (const float*)d_in[2];
    const float* Wk_T   = (const float*)d_in[3];
    const float* Wv_T   = (const float*)d_in[4];
    const float* Wq_S   = (const float*)d_in[5];
    const float* Wk_S   = (const float*)d_in[6];
    const float* Wout_T = (const float*)d_in[7];
    const float* bout_T = (const float*)d_in[8];
    const float* bias_T = (const float*)d_in[9];
    const float* bias_S = (const float*)d_in[10];
    float* out = (float*)d_out;

    constexpr int B = 16, T = 1024, N = 512, DKT = 64, DKS = 128;
    typedef unsigned short us;

    // ---- workspace layout (byte-exact reuse; peak = 146.0 MB, proven) ----
    char* w = (char*)d_ws;
    size_t off = 0;
    auto alloc = [&](size_t bytes) { char* p = w + off; off = (off + bytes + 255) & ~(size_t)255; return p; };
    us* wqkT_h = (us*)alloc(128 * 512 * 2);      // [128][512]: rows 0-63 Wq^T, 64-127 Wk^T
    us* wqkT_l = (us*)alloc(128 * 512 * 2);
    us* wvt_h  = (us*)alloc(512 * 512 * 2);      // Wv^T [512][512]
    us* wvt_l  = (us*)alloc(512 * 512 * 2);
    us* wqks_h = (us*)alloc(256 * 1024 * 2);     // rows 0-127 WqS^T, 128-255 WkS^T
    us* wqks_l = (us*)alloc(256 * 1024 * 2);
    us* wout_h = (us*)alloc(512 * 512 * 2);      // Wout^T
    us* wout_l = (us*)alloc(512 * 512 * 2);
    us* qk_h   = (us*)alloc((size_t)16384 * 128 * 2);  // temporal q|k; reused as spatial [8192][256]
    us* qk_l   = (us*)alloc((size_t)16384 * 128 * 2);
    float* attnT = (float*)alloc((size_t)B * T * T * 4); // logits/P in place; later attnS + spare
    us* vT_h   = (us*)alloc((size_t)B * N * T * 2);      // v^T planes; reused as out2
    us* vT_l   = (us*)alloc((size_t)B * N * T * 2);
    us* outT_h = (us*)alloc((size_t)B * T * N * 2);
    us* outT_l = (us*)alloc((size_t)B * T * N * 2);
    float* attnS = attnT;          // [B][512][512] fp32, after attnT's last read
    us* out2_h = vT_h;             // after vT's last read
    us* out2_l = vT_l;

    const float scale_T = 0.125f;
    const float scale_S = 0.088388347648318447f;
    const int BIG = 1 << 30;

    // ---- weight transposes + splits ----
    dim3 tb(32, 8);
    transpose_split<<<dim3(2, 16),  tb, 0, stream>>>(Wq_T,   wqkT_h, wqkT_l, 512, 64,   0, 512);
    transpose_split<<<dim3(2, 16),  tb, 0, stream>>>(Wk_T,   wqkT_h, wqkT_l, 512, 64,  64, 512);
    transpose_split<<<dim3(16, 16), tb, 0, stream>>>(Wv_T,   wvt_h,  wvt_l,  512, 512,  0, 512);
    transpose_split<<<dim3(4, 32),  tb, 0, stream>>>(Wq_S,   wqks_h, wqks_l, 1024, 128, 0, 1024);
    transpose_split<<<dim3(4, 32),  tb, 0, stream>>>(Wk_S,   wqks_h, wqks_l, 1024, 128, 128, 1024);
    transpose_split<<<dim3(16, 16), tb, 0, stream>>>(Wout_T, wout_h, wout_l, 512, 512,  0, 512);

    // ---- temporal chain ----
    // qk = x_T @ [Wq|Wk]^T  (cols<64 get *scale_T + bias_T)   [16384 x 128], K=512, 3-pass
    gemm_nt<128, 128, 1, 3, 2, true><<<dim3(1, 128, 1), 256, 0, stream>>>(
        x_T, nullptr, wqkT_h, wqkT_l, qk_h, qk_l, bias_T,
        512, 512, 512, 128, 0, 0, 0, scale_T, 64);
    // v^T_b = Wv^T @ x_b^T   [512 x 1024] per b, K=512, 3-pass
    gemm_nt<128, 128, 3, 1, 2, false><<<dim3(8, 4, B), 256, 0, stream>>>(
        wvt_h, wvt_l, x_T, nullptr, vT_h, vT_l, nullptr,
        512, 512, 512, 1024, 0, (long)T * N, (long)N * T, 1.0f, 0);
    // logits_T = q_b @ k_b^T  [1024 x 1024] per b, K=64, 3-pass, fp32 out
    gemm_nt<128, 128, 3, 3, 0, false><<<dim3(8, 8, B), 256, 0, stream>>>(
        qk_h, qk_l, qk_h + 64, qk_l + 64, attnT, nullptr, nullptr,
        64, 128, 128, 1024, (long)T * 128, (long)T * 128, (long)T * T, 1.0f, 0);
    softmax_rows<1024><<<B * T, 256, 0, stream>>>(attnT);
    // outT = P_b @ v_b  (NT vs v^T)  [1024 x 512] per b, K=1024, 2-pass (P hi-only)
    gemm_nt<128, 128, 0, 3, 2, false><<<dim3(4, 8, B), 256, 0, stream>>>(
        attnT, nullptr, vT_h, vT_l, outT_h, outT_l, nullptr,
        1024, 1024, 1024, 512, (long)T * T, (long)N * T, (long)T * N, 1.0f, 0);

    // ---- spatial chain (reuses qk region and attnT region) ----
    // qkS = x_S @ [WqS|WkS]^T  (cols<128 get *scale_S + bias_S)  [8192 x 256], K=1024, 3-pass
    gemm_nt<128, 128, 1, 3, 2, true><<<dim3(2, 64, 1), 256, 0, stream>>>(
        x_S, nullptr, wqks_h, wqks_l, qk_h, qk_l, bias_S,
        1024, 1024, 1024, 256, 0, 0, 0, scale_S, 128);
    // logits_S = qS_b @ kS_b^T  [512 x 512] per b, K=128, 3-pass, fp32 out
    gemm_nt<128, 128, 3, 3, 0, false><<<dim3(4, 4, B), 256, 0, stream>>>(
        qk_h, qk_l, qk_h + 128, qk_l + 128, attnS, nullptr, nullptr,
        128, 256, 256, 512, (long)N * 256, (long)N * 256, (long)N * N, 1.0f, 0);
    softmax_rows<512><<<B * N, 256, 0, stream>>>(attnS);
    // out2 = outT_b @ P_S_b^T  [1024 x 512] per b, K=512, 2-pass (P_S hi-only)
    gemm_nt<128, 128, 3, 0, 2, false><<<dim3(4, 8, B), 256, 0, stream>>>(
        outT_h, outT_l, attnS, nullptr, out2_h, out2_l, nullptr,
        512, 512, 512, 512, (long)T * N, (long)N * N, (long)T * N, 1.0f, 0);
    // out[b,i,t] = (out2_b @ Wout + bout)^T  [512 x 1024] per b via STORE_T, K=512, 3-pass
    gemm_nt<128, 128, 3, 3, 1, true><<<dim3(4, 8, B), 256, 0, stream>>>(
        out2_h, out2_l, wout_h, wout_l, out, nullptr, bout_T,
        512, 512, 512, 1024, (long)T * N, 0, (long)N * T, 1.0f, BIG);
}

// Round 4
// 289.685 us; speedup vs baseline: 1.4873x; 1.1407x over previous
//
#include <hip/hip_runtime.h>
#include <cstddef>

typedef short short8 __attribute__((ext_vector_type(8)));
typedef unsigned short ushortx8 __attribute__((ext_vector_type(8)));
typedef float floatx4 __attribute__((ext_vector_type(4)));

__device__ __forceinline__ unsigned int bf16_rne(float x) {
    unsigned int u = __float_as_uint(x);
    return (u + 0x7fffu + ((u >> 16) & 1u)) >> 16;
}

// fp32x4 -> bf16 hi pack + bf16 lo (residual) pack
__device__ __forceinline__ void split4(const floatx4 v,
                                       unsigned long long& hp,
                                       unsigned long long& lp) {
    unsigned int h[4], l[4];
    #pragma unroll
    for (int j = 0; j < 4; ++j) {
        h[j] = bf16_rne(v[j]);
        float hf = __uint_as_float(h[j] << 16);
        l[j] = bf16_rne(v[j] - hf);
    }
    hp = (unsigned long long)(h[0] | (h[1] << 16)) |
         ((unsigned long long)(h[2] | (h[3] << 16)) << 32);
    lp = (unsigned long long)(l[0] | (l[1] << 16)) |
         ((unsigned long long)(l[2] | (l[3] << 16)) << 32);
}

__device__ __forceinline__ unsigned long long pack_hi4(const floatx4 v) {
    unsigned int h0 = bf16_rne(v[0]), h1 = bf16_rne(v[1]);
    unsigned int h2 = bf16_rne(v[2]), h3 = bf16_rne(v[3]);
    return (unsigned long long)(h0 | (h1 << 16)) |
           ((unsigned long long)(h2 | (h3 << 16)) << 32);
}

// ---------------------------------------------------------------------------
// NT GEMM, operands fp32 (split during staging) or pre-split bf16 planes.
//   AMODE/BMODE: 0 = fp32 src, hi only; 1 = fp32 src, hi+lo;
//                2 = bf16 planes, hi only; 3 = bf16 planes, hi+lo
//   MFMA passes: Ah*Bh (+ Al*Bh if ALO) (+ Ah*Bl if BLO)
//   OUTMODE: 0 = fp32 row-major; 1 = fp32 transposed (float4 along m);
//            2 = bf16 hi/lo planes
//   Epilogue: for col gn < nsplit: val = acc*alpha + bias[gn]; else val = acc.
// Block = 256 threads = 4 waves (2x2), wave owns (BM/2)x(BN/2).
// lda/ldb/sA/sB in ELEMENTS of the source type (float or ushort).
// ---------------------------------------------------------------------------
template<int BM, int BN, int AMODE, int BMODE, int OUTMODE, bool HASBIAS>
__global__ __launch_bounds__(256, 2)
void gemm_nt(const void* __restrict__ Ah_, const void* __restrict__ Al_,
             const void* __restrict__ Bh_, const void* __restrict__ Bl_,
             void* __restrict__ C_, void* __restrict__ Cl_,
             const float* __restrict__ bias,
             int K, int lda, int ldb, int ldc,
             long sA, long sB, long sC, float alpha, int nsplit)
{
    constexpr bool ALO = (AMODE == 1 || AMODE == 3);
    constexpr bool BLO = (BMODE == 1 || BMODE == 3);
    constexpr int LS = 40;   // 32 + 8 pad halves -> 80B rows, 2-way bank alias (free)
    __shared__ unsigned short Ash[BM][LS];
    __shared__ unsigned short Als[ALO ? BM : 1][LS];
    __shared__ unsigned short Bsh[BN][LS];
    __shared__ unsigned short Bls[BLO ? BN : 1][LS];

    const int b   = blockIdx.z;
    const int bm0 = blockIdx.y * BM;
    const int bn0 = blockIdx.x * BN;
    const int tid  = threadIdx.x;
    const int lane = tid & 63;
    const int wid  = tid >> 6;
    const int wr = wid >> 1, wc = wid & 1;
    constexpr int WM = BM / 2, WN = BN / 2;
    constexpr int FM = WM / 16, FN = WN / 16;
    floatx4 acc[FM][FN] = {};
    const int l15  = lane & 15;
    const int koff = (lane >> 4) * 8;

    for (int k0 = 0; k0 < K; k0 += 32) {
        // ---- stage A (BM x 32) ----
        if (AMODE <= 1) {
            const float* A = (const float*)Ah_ + (long)b * sA;
            #pragma unroll
            for (int i = 0; i < (BM * 32) / 1024; ++i) {
                int flat = i * 1024 + tid * 4;
                int r = flat >> 5, c = flat & 31;
                floatx4 v = *(const floatx4*)(A + (long)(bm0 + r) * lda + k0 + c);
                if (AMODE == 1) {
                    unsigned long long hp, lp; split4(v, hp, lp);
                    *(unsigned long long*)&Ash[r][c] = hp;
                    *(unsigned long long*)&Als[r][c] = lp;
                } else {
                    *(unsigned long long*)&Ash[r][c] = pack_hi4(v);
                }
            }
        } else {
            const unsigned short* A  = (const unsigned short*)Ah_ + (long)b * sA;
            const unsigned short* Al = (const unsigned short*)Al_ + (long)b * sA;
            #pragma unroll
            for (int i = 0; i < (BM * 32) / 2048; ++i) {
                int flat = i * 2048 + tid * 8;
                int r = flat >> 5, c = flat & 31;
                *(ushortx8*)&Ash[r][c] = *(const ushortx8*)(A + (long)(bm0 + r) * lda + k0 + c);
                if (AMODE == 3)
                    *(ushortx8*)&Als[r][c] = *(const ushortx8*)(Al + (long)(bm0 + r) * lda + k0 + c);
            }
        }
        // ---- stage B (BN x 32) ----
        if (BMODE <= 1) {
            const float* Bp = (const float*)Bh_ + (long)b * sB;
            #pragma unroll
            for (int i = 0; i < (BN * 32) / 1024; ++i) {
                int flat = i * 1024 + tid * 4;
                int r = flat >> 5, c = flat & 31;
                floatx4 v = *(const floatx4*)(Bp + (long)(bn0 + r) * ldb + k0 + c);
                if (BMODE == 1) {
                    unsigned long long hp, lp; split4(v, hp, lp);
                    *(unsigned long long*)&Bsh[r][c] = hp;
                    *(unsigned long long*)&Bls[r][c] = lp;
                } else {
                    *(unsigned long long*)&Bsh[r][c] = pack_hi4(v);
                }
            }
        } else {
            const unsigned short* Bp = (const unsigned short*)Bh_ + (long)b * sB;
            const unsigned short* Bl = (const unsigned short*)Bl_ + (long)b * sB;
            #pragma unroll
            for (int i = 0; i < (BN * 32) / 2048; ++i) {
                int flat = i * 2048 + tid * 8;
                int r = flat >> 5, c = flat & 31;
                *(ushortx8*)&Bsh[r][c] = *(const ushortx8*)(Bp + (long)(bn0 + r) * ldb + k0 + c);
                if (BMODE == 3)
                    *(ushortx8*)&Bls[r][c] = *(const ushortx8*)(Bl + (long)(bn0 + r) * ldb + k0 + c);
            }
        }
        __syncthreads();

        short8 ah[FM], al[FM], bh[FN], bl[FN];
        #pragma unroll
        for (int mi = 0; mi < FM; ++mi) {
            ah[mi] = *(const short8*)&Ash[wr * WM + mi * 16 + l15][koff];
            if (ALO) al[mi] = *(const short8*)&Als[wr * WM + mi * 16 + l15][koff];
        }
        #pragma unroll
        for (int ni = 0; ni < FN; ++ni) {
            bh[ni] = *(const short8*)&Bsh[wc * WN + ni * 16 + l15][koff];
            if (BLO) bl[ni] = *(const short8*)&Bls[wc * WN + ni * 16 + l15][koff];
        }

        #pragma unroll
        for (int mi = 0; mi < FM; ++mi)
            #pragma unroll
            for (int ni = 0; ni < FN; ++ni) {
                if (ALO)
                    acc[mi][ni] = __builtin_amdgcn_mfma_f32_16x16x32_bf16(
                        al[mi], bh[ni], acc[mi][ni], 0, 0, 0);
                if (BLO)
                    acc[mi][ni] = __builtin_amdgcn_mfma_f32_16x16x32_bf16(
                        ah[mi], bl[ni], acc[mi][ni], 0, 0, 0);
                acc[mi][ni] = __builtin_amdgcn_mfma_f32_16x16x32_bf16(
                    ah[mi], bh[ni], acc[mi][ni], 0, 0, 0);
            }
        __syncthreads();
    }

    // ---- epilogue: C row = (lane>>4)*4 + reg, col = lane&15 ----
    const int rq = (lane >> 4) * 4;
    #pragma unroll
    for (int mi = 0; mi < FM; ++mi) {
        #pragma unroll
        for (int ni = 0; ni < FN; ++ni) {
            int gm = bm0 + wr * WM + mi * 16 + rq;
            int gn = bn0 + wc * WN + ni * 16 + l15;
            float ae = (gn < nsplit) ? alpha : 1.0f;
            float be = 0.f;
            if (HASBIAS) be = (gn < nsplit) ? bias[gn] : 0.0f;
            float vals[4];
            #pragma unroll
            for (int j = 0; j < 4; ++j) vals[j] = acc[mi][ni][j] * ae + be;
            if (OUTMODE == 0) {
                float* C = (float*)C_ + (long)b * sC;
                #pragma unroll
                for (int j = 0; j < 4; ++j) C[(long)(gm + j) * ldc + gn] = vals[j];
            } else if (OUTMODE == 1) {
                float* C = (float*)C_ + (long)b * sC;
                floatx4 o;
                #pragma unroll
                for (int j = 0; j < 4; ++j) o[j] = vals[j];
                *(floatx4*)(C + (long)gn * ldc + gm) = o;
            } else {
                unsigned short* Ch = (unsigned short*)C_ + (long)b * sC;
                unsigned short* Cl = (unsigned short*)Cl_ + (long)b * sC;
                #pragma unroll
                for (int j = 0; j < 4; ++j) {
                    unsigned int h = bf16_rne(vals[j]);
                    float hf = __uint_as_float(h << 16);
                    unsigned int lo = bf16_rne(vals[j] - hf);
                    Ch[(long)(gm + j) * ldc + gn] = (unsigned short)h;
                    Cl[(long)(gm + j) * ldc + gn] = (unsigned short)lo;
                }
            }
        }
    }
}

// ---------------------------------------------------------------------------
// Row softmax in place (fp32 in). If BF16OUT, write P as packed bf16 into the
// FIRST HALF of the same row's storage (row stride stays COLS floats = 2*COLS
// ushorts). Block reads entire row into registers before any write (barrier-
// separated), so in-place is safe.
// ---------------------------------------------------------------------------
template<int COLS, bool BF16OUT>
__global__ __launch_bounds__(256)
void softmax_rows(float* __restrict__ data)
{
    constexpr int NPT = COLS / 256;
    float* p = data + (long)blockIdx.x * COLS;
    const int t = threadIdx.x;
    const int wid = t >> 6;
    __shared__ float red[4];

    float v[NPT];
    float m = -1e30f;
    #pragma unroll
    for (int i = 0; i < NPT; ++i) {
        v[i] = p[t + i * 256];
        m = fmaxf(m, v[i]);
    }
    #pragma unroll
    for (int off = 32; off; off >>= 1) m = fmaxf(m, __shfl_xor(m, off));
    if ((t & 63) == 0) red[wid] = m;
    __syncthreads();
    m = fmaxf(fmaxf(red[0], red[1]), fmaxf(red[2], red[3]));

    float s = 0.f;
    #pragma unroll
    for (int i = 0; i < NPT; ++i) {
        v[i] = __expf(v[i] - m);
        s += v[i];
    }
    #pragma unroll
    for (int off = 32; off; off >>= 1) s += __shfl_xor(s, off);
    __syncthreads();
    if ((t & 63) == 0) red[wid] = s;
    __syncthreads();
    s = red[0] + red[1] + red[2] + red[3];
    float inv = 1.f / s;
    if (BF16OUT) {
        unsigned short* pu = (unsigned short*)p;
        #pragma unroll
        for (int i = 0; i < NPT; ++i)
            pu[t + i * 256] = (unsigned short)bf16_rne(v[i] * inv);
    } else {
        #pragma unroll
        for (int i = 0; i < NPT; ++i) p[t + i * 256] = v[i] * inv;
    }
}

// ---------------------------------------------------------------------------
// Transpose + split: in[R][C] fp32 -> outH/outL[(c+rowOff)][r] bf16 planes
// block (32,8), grid (C/32, R/32)
// ---------------------------------------------------------------------------
__global__ __launch_bounds__(256)
void transpose_split(const float* __restrict__ in,
                     unsigned short* __restrict__ outH,
                     unsigned short* __restrict__ outL,
                     int R, int C, int rowOff, int ldo)
{
    __shared__ float tile[32][33];
    const int tc = blockIdx.x * 32, tr = blockIdx.y * 32;
    const int x = threadIdx.x, y = threadIdx.y;
    #pragma unroll
    for (int i = 0; i < 32; i += 8)
        tile[y + i][x] = in[(long)(tr + y + i) * C + tc + x];
    __syncthreads();
    #pragma unroll
    for (int i = 0; i < 32; i += 8) {
        float v = tile[x][y + i];
        unsigned int h = bf16_rne(v);
        float hf = __uint_as_float(h << 16);
        unsigned int lo = bf16_rne(v - hf);
        long idx = (long)(tc + y + i + rowOff) * ldo + tr + x;
        outH[idx] = (unsigned short)h;
        outL[idx] = (unsigned short)lo;
    }
}

extern "C" void kernel_launch(void* const* d_in, const int* in_sizes, int n_in,
                              void* d_out, int out_size, void* d_ws, size_t ws_size,
                              hipStream_t stream)
{
    (void)in_sizes; (void)n_in; (void)out_size; (void)ws_size;
    const float* x_T    = (const float*)d_in[0];
    const float* x_S    = (const float*)d_in[1];
    const float* Wq_T   = (const float*)d_in[2];
    const float* Wk_T   = (const float*)d_in[3];
    const float* Wv_T   = (const float*)d_in[4];
    const float* Wq_S   = (const float*)d_in[5];
    const float* Wk_S   = (const float*)d_in[6];
    const float* Wout_T = (const float*)d_in[7];
    const float* bout_T = (const float*)d_in[8];
    const float* bias_T = (const float*)d_in[9];
    const float* bias_S = (const float*)d_in[10];
    float* out = (float*)d_out;

    constexpr int B = 16, T = 1024, N = 512, DKT = 64, DKS = 128;
    typedef unsigned short us;

    // ---- workspace layout (region reuse; peak ~146 MB, proven) ----
    char* w = (char*)d_ws;
    size_t off = 0;
    auto alloc = [&](size_t bytes) { char* p = w + off; off = (off + bytes + 255) & ~(size_t)255; return p; };
    us* wqkT_h = (us*)alloc(128 * 512 * 2);      // [128][512]: rows 0-63 Wq^T, 64-127 Wk^T
    us* wqkT_l = (us*)alloc(128 * 512 * 2);
    us* wvt_h  = (us*)alloc(512 * 512 * 2);      // Wv^T [512][512]
    us* wvt_l  = (us*)alloc(512 * 512 * 2);
    us* wqks_h = (us*)alloc(256 * 1024 * 2);     // rows 0-127 WqS^T, 128-255 WkS^T
    us* wqks_l = (us*)alloc(256 * 1024 * 2);
    us* wout_h = (us*)alloc(512 * 512 * 2);      // Wout^T
    us* wout_l = (us*)alloc(512 * 512 * 2);
    us* qk_h   = (us*)alloc((size_t)16384 * 128 * 2);  // temporal q|k; reused as spatial [8192][256]
    us* qk_l   = (us*)alloc((size_t)16384 * 128 * 2);
    float* attnT = (float*)alloc((size_t)B * T * T * 4); // logits fp32; P bf16 in place
    us* vT_h   = (us*)alloc((size_t)B * N * T * 2);      // v^T planes; reused as out2
    us* vT_l   = (us*)alloc((size_t)B * N * T * 2);
    us* outT_h = (us*)alloc((size_t)B * T * N * 2);
    us* outT_l = (us*)alloc((size_t)B * T * N * 2);
    float* attnS = attnT;          // [B][512][512] fp32, after attnT's last read
    us* out2_h = vT_h;             // after vT's last read
    us* out2_l = vT_l;

    const float scale_T = 0.125f;
    const float scale_S = 0.088388347648318447f;
    const int BIG = 1 << 30;

    // ---- weight transposes + splits ----
    dim3 tb(32, 8);
    transpose_split<<<dim3(2, 16),  tb, 0, stream>>>(Wq_T,   wqkT_h, wqkT_l, 512, 64,   0, 512);
    transpose_split<<<dim3(2, 16),  tb, 0, stream>>>(Wk_T,   wqkT_h, wqkT_l, 512, 64,  64, 512);
    transpose_split<<<dim3(16, 16), tb, 0, stream>>>(Wv_T,   wvt_h,  wvt_l,  512, 512,  0, 512);
    transpose_split<<<dim3(4, 32),  tb, 0, stream>>>(Wq_S,   wqks_h, wqks_l, 1024, 128, 0, 1024);
    transpose_split<<<dim3(4, 32),  tb, 0, stream>>>(Wk_S,   wqks_h, wqks_l, 1024, 128, 128, 1024);
    transpose_split<<<dim3(16, 16), tb, 0, stream>>>(Wout_T, wout_h, wout_l, 512, 512,  0, 512);

    // ---- temporal chain ----
    // qk = x_T @ [Wq|Wk]^T  (cols<64: *scale_T + bias_T)  [16384 x 128], K=512, 3-pass
    // 64x64 tiles -> 512 blocks (grid-starvation fix)
    gemm_nt<64, 64, 1, 3, 2, true><<<dim3(2, 256, 1), 256, 0, stream>>>(
        x_T, nullptr, wqkT_h, wqkT_l, qk_h, qk_l, bias_T,
        512, 512, 512, 128, 0, 0, 0, scale_T, 64);
    // v^T_b = Wv^T @ x_b^T   [512 x 1024] per b, K=512, 3-pass
    gemm_nt<128, 128, 3, 1, 2, false><<<dim3(8, 4, B), 256, 0, stream>>>(
        wvt_h, wvt_l, x_T, nullptr, vT_h, vT_l, nullptr,
        512, 512, 512, 1024, 0, (long)T * N, (long)N * T, 1.0f, 0);
    // logits_T = q_b @ k_b^T  [1024 x 1024] per b, K=64, 3-pass, fp32 out
    gemm_nt<128, 128, 3, 3, 0, false><<<dim3(8, 8, B), 256, 0, stream>>>(
        qk_h, qk_l, qk_h + 64, qk_l + 64, attnT, nullptr, nullptr,
        64, 128, 128, 1024, (long)T * 128, (long)T * 128, (long)T * T, 1.0f, 0);
    // softmax -> P bf16 in place (row stride 2048 ushorts, first 1024 used)
    softmax_rows<1024, true><<<B * T, 256, 0, stream>>>(attnT);
    // outT = P_b @ v_b  (NT vs v^T)  [1024 x 512] per b, K=1024, 2-pass (P hi-only bf16)
    gemm_nt<128, 128, 2, 3, 2, false><<<dim3(4, 8, B), 256, 0, stream>>>(
        attnT, nullptr, vT_h, vT_l, outT_h, outT_l, nullptr,
        1024, 2048, 1024, 512, (long)T * 2048, (long)N * T, (long)T * N, 1.0f, 0);

    // ---- spatial chain (reuses qk region and attnT region) ----
    // qkS = x_S @ [WqS|WkS]^T  (cols<128: *scale_S + bias_S)  [8192 x 256], K=1024, 3-pass
    gemm_nt<64, 64, 1, 3, 2, true><<<dim3(4, 128, 1), 256, 0, stream>>>(
        x_S, nullptr, wqks_h, wqks_l, qk_h, qk_l, bias_S,
        1024, 1024, 1024, 256, 0, 0, 0, scale_S, 128);
    // logits_S = qS_b @ kS_b^T  [512 x 512] per b, K=128, 3-pass, fp32 out
    gemm_nt<64, 64, 3, 3, 0, false><<<dim3(8, 8, B), 256, 0, stream>>>(
        qk_h, qk_l, qk_h + 128, qk_l + 128, attnS, nullptr, nullptr,
        128, 256, 256, 512, (long)N * 256, (long)N * 256, (long)N * N, 1.0f, 0);
    // softmax -> P_S bf16 in place (row stride 1024 ushorts, first 512 used)
    softmax_rows<512, true><<<B * N, 256, 0, stream>>>(attnS);
    // out2 = outT_b @ P_S_b^T  [1024 x 512] per b, K=512, 2-pass (P_S hi-only bf16)
    gemm_nt<128, 128, 3, 2, 2, false><<<dim3(4, 8, B), 256, 0, stream>>>(
        outT_h, outT_l, attnS, nullptr, out2_h, out2_l, nullptr,
        512, 512, 1024, 512, (long)T * N, (long)N * 1024, (long)T * N, 1.0f, 0);
    // out[b,i,t] = (out2_b @ Wout + bout)^T  [512 x 1024] per b via STORE_T, K=512, 3-pass
    gemm_nt<128, 128, 3, 3, 1, true><<<dim3(4, 8, B), 256, 0, stream>>>(
        out2_h, out2_l, wout_h, wout_l, out, nullptr, bout_T,
        512, 512, 512, 1024, (long)T * N, 0, (long)N * T, 1.0f, BIG);
}

// Round 5
// 280.914 us; speedup vs baseline: 1.5337x; 1.0312x over previous
//
#include <hip/hip_runtime.h>
#include <cstddef>

typedef short short8 __attribute__((ext_vector_type(8)));
typedef unsigned short ushortx8 __attribute__((ext_vector_type(8)));
typedef float floatx4 __attribute__((ext_vector_type(4)));

__device__ __forceinline__ unsigned int bf16_rne(float x) {
    unsigned int u = __float_as_uint(x);
    return (u + 0x7fffu + ((u >> 16) & 1u)) >> 16;
}

__device__ __forceinline__ void split4(const floatx4 v,
                                       unsigned long long& hp,
                                       unsigned long long& lp) {
    unsigned int h[4], l[4];
    #pragma unroll
    for (int j = 0; j < 4; ++j) {
        h[j] = bf16_rne(v[j]);
        float hf = __uint_as_float(h[j] << 16);
        l[j] = bf16_rne(v[j] - hf);
    }
    hp = (unsigned long long)(h[0] | (h[1] << 16)) |
         ((unsigned long long)(h[2] | (h[3] << 16)) << 32);
    lp = (unsigned long long)(l[0] | (l[1] << 16)) |
         ((unsigned long long)(l[2] | (l[3] << 16)) << 32);
}

__device__ __forceinline__ unsigned long long pack_hi4(const floatx4 v) {
    unsigned int h0 = bf16_rne(v[0]), h1 = bf16_rne(v[1]);
    unsigned int h2 = bf16_rne(v[2]), h3 = bf16_rne(v[3]);
    return (unsigned long long)(h0 | (h1 << 16)) |
           ((unsigned long long)(h2 | (h3 << 16)) << 32);
}

// ---------------------------------------------------------------------------
// NT GEMM, software-pipelined (reg prefetch + LDS double-buffer, 1 barrier/step)
//   AMODE/BMODE: 0 = fp32 src, hi only; 1 = fp32 src, hi+lo;
//                2 = bf16 planes, hi only; 3 = bf16 planes, hi+lo
//   MFMA passes: Ah*Bh (+ Al*Bh if ALO) (+ Ah*Bl if BLO)
//   OUTMODE: 0 = fp32 row-major; 1 = fp32 transposed (float4 along m);
//            2 = bf16 hi/lo planes
//   Epilogue: for col gn < nsplit: val = acc*alpha + bias[gn]; else val = acc.
// Block = 256 threads = 4 waves (2x2), wave owns (BM/2)x(BN/2).
// lda/ldb/sA/sB in ELEMENTS of the source type (float or ushort).
// ---------------------------------------------------------------------------
template<int BM, int BN, int AMODE, int BMODE, int OUTMODE, bool HASBIAS>
__global__ __launch_bounds__(256, 2)
void gemm_nt(const void* __restrict__ Ah_, const void* __restrict__ Al_,
             const void* __restrict__ Bh_, const void* __restrict__ Bl_,
             void* __restrict__ C_, void* __restrict__ Cl_,
             const float* __restrict__ bias,
             int K, int lda, int ldb, int ldc,
             long sA, long sB, long sC, float alpha, int nsplit)
{
    constexpr bool ALO = (AMODE == 1 || AMODE == 3);
    constexpr bool BLO = (BMODE == 1 || BMODE == 3);
    constexpr int LS = 40;   // 32 + 8 pad halves -> 80B rows, 2-way bank alias (free)
    __shared__ unsigned short Ash[2][BM][LS];
    __shared__ unsigned short Als[2][ALO ? BM : 1][LS];
    __shared__ unsigned short Bsh[2][BN][LS];
    __shared__ unsigned short Bls[2][BLO ? BN : 1][LS];

    const int b   = blockIdx.z;
    const int bm0 = blockIdx.y * BM;
    const int bn0 = blockIdx.x * BN;
    const int tid  = threadIdx.x;
    const int lane = tid & 63;
    const int wid  = tid >> 6;
    const int wr = wid >> 1, wc = wid & 1;
    constexpr int WM = BM / 2, WN = BN / 2;
    constexpr int FM = WM / 16, FN = WN / 16;
    floatx4 acc[FM][FN] = {};
    const int l15  = lane & 15;
    const int koff = (lane >> 4) * 8;

    // per-thread register staging buffers
    constexpr int NAF = (AMODE <= 1) ? (BM * 32) / 1024 : 1;
    constexpr int NAH = (AMODE >= 2) ? (BM * 32) / 2048 : 1;
    constexpr int NBF = (BMODE <= 1) ? (BN * 32) / 1024 : 1;
    constexpr int NBH = (BMODE >= 2) ? (BN * 32) / 2048 : 1;
    floatx4  aF[NAF], bF[NBF];
    ushortx8 aH[NAH], aL[NAH], bH[NBH], bL[NBH];

    auto loadA = [&](int k0) {
        if (AMODE <= 1) {
            const float* A = (const float*)Ah_ + (long)b * sA;
            #pragma unroll
            for (int i = 0; i < NAF; ++i) {
                int flat = i * 1024 + tid * 4;
                int r = flat >> 5, c = flat & 31;
                aF[i] = *(const floatx4*)(A + (long)(bm0 + r) * lda + k0 + c);
            }
        } else {
            const unsigned short* A  = (const unsigned short*)Ah_ + (long)b * sA;
            const unsigned short* Al = (const unsigned short*)Al_ + (long)b * sA;
            #pragma unroll
            for (int i = 0; i < NAH; ++i) {
                int flat = i * 2048 + tid * 8;
                int r = flat >> 5, c = flat & 31;
                aH[i] = *(const ushortx8*)(A + (long)(bm0 + r) * lda + k0 + c);
                if (AMODE == 3)
                    aL[i] = *(const ushortx8*)(Al + (long)(bm0 + r) * lda + k0 + c);
            }
        }
    };
    auto loadB = [&](int k0) {
        if (BMODE <= 1) {
            const float* Bp = (const float*)Bh_ + (long)b * sB;
            #pragma unroll
            for (int i = 0; i < NBF; ++i) {
                int flat = i * 1024 + tid * 4;
                int r = flat >> 5, c = flat & 31;
                bF[i] = *(const floatx4*)(Bp + (long)(bn0 + r) * ldb + k0 + c);
            }
        } else {
            const unsigned short* Bp = (const unsigned short*)Bh_ + (long)b * sB;
            const unsigned short* Bl = (const unsigned short*)Bl_ + (long)b * sB;
            #pragma unroll
            for (int i = 0; i < NBH; ++i) {
                int flat = i * 2048 + tid * 8;
                int r = flat >> 5, c = flat & 31;
                bH[i] = *(const ushortx8*)(Bp + (long)(bn0 + r) * ldb + k0 + c);
                if (BMODE == 3)
                    bL[i] = *(const ushortx8*)(Bl + (long)(bn0 + r) * ldb + k0 + c);
            }
        }
    };
    auto writeA = [&](int bf) {
        if (AMODE <= 1) {
            #pragma unroll
            for (int i = 0; i < NAF; ++i) {
                int flat = i * 1024 + tid * 4;
                int r = flat >> 5, c = flat & 31;
                if (AMODE == 1) {
                    unsigned long long hp, lp; split4(aF[i], hp, lp);
                    *(unsigned long long*)&Ash[bf][r][c] = hp;
                    *(unsigned long long*)&Als[bf][r][c] = lp;
                } else {
                    *(unsigned long long*)&Ash[bf][r][c] = pack_hi4(aF[i]);
                }
            }
        } else {
            #pragma unroll
            for (int i = 0; i < NAH; ++i) {
                int flat = i * 2048 + tid * 8;
                int r = flat >> 5, c = flat & 31;
                *(ushortx8*)&Ash[bf][r][c] = aH[i];
                if (AMODE == 3) *(ushortx8*)&Als[bf][r][c] = aL[i];
            }
        }
    };
    auto writeB = [&](int bf) {
        if (BMODE <= 1) {
            #pragma unroll
            for (int i = 0; i < NBF; ++i) {
                int flat = i * 1024 + tid * 4;
                int r = flat >> 5, c = flat & 31;
                if (BMODE == 1) {
                    unsigned long long hp, lp; split4(bF[i], hp, lp);
                    *(unsigned long long*)&Bsh[bf][r][c] = hp;
                    *(unsigned long long*)&Bls[bf][r][c] = lp;
                } else {
                    *(unsigned long long*)&Bsh[bf][r][c] = pack_hi4(bF[i]);
                }
            }
        } else {
            #pragma unroll
            for (int i = 0; i < NBH; ++i) {
                int flat = i * 2048 + tid * 8;
                int r = flat >> 5, c = flat & 31;
                *(ushortx8*)&Bsh[bf][r][c] = bH[i];
                if (BMODE == 3) *(ushortx8*)&Bls[bf][r][c] = bL[i];
            }
        }
    };
    auto compute = [&](int bf) {
        short8 ah[FM], al[FM], bh[FN], bl[FN];
        #pragma unroll
        for (int mi = 0; mi < FM; ++mi) {
            ah[mi] = *(const short8*)&Ash[bf][wr * WM + mi * 16 + l15][koff];
            if (ALO) al[mi] = *(const short8*)&Als[bf][wr * WM + mi * 16 + l15][koff];
        }
        #pragma unroll
        for (int ni = 0; ni < FN; ++ni) {
            bh[ni] = *(const short8*)&Bsh[bf][wc * WN + ni * 16 + l15][koff];
            if (BLO) bl[ni] = *(const short8*)&Bls[bf][wc * WN + ni * 16 + l15][koff];
        }
        #pragma unroll
        for (int mi = 0; mi < FM; ++mi)
            #pragma unroll
            for (int ni = 0; ni < FN; ++ni) {
                if (ALO)
                    acc[mi][ni] = __builtin_amdgcn_mfma_f32_16x16x32_bf16(
                        al[mi], bh[ni], acc[mi][ni], 0, 0, 0);
                if (BLO)
                    acc[mi][ni] = __builtin_amdgcn_mfma_f32_16x16x32_bf16(
                        ah[mi], bl[ni], acc[mi][ni], 0, 0, 0);
                acc[mi][ni] = __builtin_amdgcn_mfma_f32_16x16x32_bf16(
                    ah[mi], bh[ni], acc[mi][ni], 0, 0, 0);
            }
    };

    // ---- pipelined K loop: 1 barrier per step ----
    loadA(0); loadB(0);
    writeA(0); writeB(0);
    __syncthreads();
    int cur = 0;
    for (int k0 = 32; k0 < K; k0 += 32) {
        loadA(k0); loadB(k0);   // prefetch next tile (VMEM in flight under MFMA)
        compute(cur);
        writeA(cur ^ 1); writeB(cur ^ 1);  // other buffer: no barrier before write
        __syncthreads();
        cur ^= 1;
    }
    compute(cur);

    // ---- epilogue: C row = (lane>>4)*4 + reg, col = lane&15 ----
    const int rq = (lane >> 4) * 4;
    #pragma unroll
    for (int mi = 0; mi < FM; ++mi) {
        #pragma unroll
        for (int ni = 0; ni < FN; ++ni) {
            int gm = bm0 + wr * WM + mi * 16 + rq;
            int gn = bn0 + wc * WN + ni * 16 + l15;
            float ae = (gn < nsplit) ? alpha : 1.0f;
            float be = 0.f;
            if (HASBIAS) be = (gn < nsplit) ? bias[gn] : 0.0f;
            float vals[4];
            #pragma unroll
            for (int j = 0; j < 4; ++j) vals[j] = acc[mi][ni][j] * ae + be;
            if (OUTMODE == 0) {
                float* C = (float*)C_ + (long)b * sC;
                #pragma unroll
                for (int j = 0; j < 4; ++j) C[(long)(gm + j) * ldc + gn] = vals[j];
            } else if (OUTMODE == 1) {
                float* C = (float*)C_ + (long)b * sC;
                floatx4 o;
                #pragma unroll
                for (int j = 0; j < 4; ++j) o[j] = vals[j];
                *(floatx4*)(C + (long)gn * ldc + gm) = o;
            } else {
                unsigned short* Ch = (unsigned short*)C_ + (long)b * sC;
                unsigned short* Cl = (unsigned short*)Cl_ + (long)b * sC;
                #pragma unroll
                for (int j = 0; j < 4; ++j) {
                    unsigned int h = bf16_rne(vals[j]);
                    float hf = __uint_as_float(h << 16);
                    unsigned int lo = bf16_rne(vals[j] - hf);
                    Ch[(long)(gm + j) * ldc + gn] = (unsigned short)h;
                    Cl[(long)(gm + j) * ldc + gn] = (unsigned short)lo;
                }
            }
        }
    }
}

// ---------------------------------------------------------------------------
// Row softmax in place (fp32 in). If BF16OUT, write P as packed bf16 into the
// FIRST HALF of the same row's storage (row stride stays COLS floats).
// Block reads entire row into registers before any write, so in-place is safe.
// ---------------------------------------------------------------------------
template<int COLS, bool BF16OUT>
__global__ __launch_bounds__(256)
void softmax_rows(float* __restrict__ data)
{
    constexpr int NPT = COLS / 256;
    float* p = data + (long)blockIdx.x * COLS;
    const int t = threadIdx.x;
    const int wid = t >> 6;
    __shared__ float red[4];

    float v[NPT];
    float m = -1e30f;
    #pragma unroll
    for (int i = 0; i < NPT; ++i) {
        v[i] = p[t + i * 256];
        m = fmaxf(m, v[i]);
    }
    #pragma unroll
    for (int off = 32; off; off >>= 1) m = fmaxf(m, __shfl_xor(m, off));
    if ((t & 63) == 0) red[wid] = m;
    __syncthreads();
    m = fmaxf(fmaxf(red[0], red[1]), fmaxf(red[2], red[3]));

    float s = 0.f;
    #pragma unroll
    for (int i = 0; i < NPT; ++i) {
        v[i] = __expf(v[i] - m);
        s += v[i];
    }
    #pragma unroll
    for (int off = 32; off; off >>= 1) s += __shfl_xor(s, off);
    __syncthreads();
    if ((t & 63) == 0) red[wid] = s;
    __syncthreads();
    s = red[0] + red[1] + red[2] + red[3];
    float inv = 1.f / s;
    if (BF16OUT) {
        unsigned short* pu = (unsigned short*)p;
        #pragma unroll
        for (int i = 0; i < NPT; ++i)
            pu[t + i * 256] = (unsigned short)bf16_rne(v[i] * inv);
    } else {
        #pragma unroll
        for (int i = 0; i < NPT; ++i) p[t + i * 256] = v[i] * inv;
    }
}

// ---------------------------------------------------------------------------
// Transpose + split: in[R][C] fp32 -> outH/outL[(c+rowOff)][r] bf16 planes
// block (32,8), grid (C/32, R/32)
// ---------------------------------------------------------------------------
__global__ __launch_bounds__(256)
void transpose_split(const float* __restrict__ in,
                     unsigned short* __restrict__ outH,
                     unsigned short* __restrict__ outL,
                     int R, int C, int rowOff, int ldo)
{
    __shared__ float tile[32][33];
    const int tc = blockIdx.x * 32, tr = blockIdx.y * 32;
    const int x = threadIdx.x, y = threadIdx.y;
    #pragma unroll
    for (int i = 0; i < 32; i += 8)
        tile[y + i][x] = in[(long)(tr + y + i) * C + tc + x];
    __syncthreads();
    #pragma unroll
    for (int i = 0; i < 32; i += 8) {
        float v = tile[x][y + i];
        unsigned int h = bf16_rne(v);
        float hf = __uint_as_float(h << 16);
        unsigned int lo = bf16_rne(v - hf);
        long idx = (long)(tc + y + i + rowOff) * ldo + tr + x;
        outH[idx] = (unsigned short)h;
        outL[idx] = (unsigned short)lo;
    }
}

extern "C" void kernel_launch(void* const* d_in, const int* in_sizes, int n_in,
                              void* d_out, int out_size, void* d_ws, size_t ws_size,
                              hipStream_t stream)
{
    (void)in_sizes; (void)n_in; (void)out_size; (void)ws_size;
    const float* x_T    = (const float*)d_in[0];
    const float* x_S    = (const float*)d_in[1];
    const float* Wq_T   = (const float*)d_in[2];
    const float* Wk_T   = (const float*)d_in[3];
    const float* Wv_T   = (const float*)d_in[4];
    const float* Wq_S   = (const float*)d_in[5];
    const float* Wk_S   = (const float*)d_in[6];
    const float* Wout_T = (const float*)d_in[7];
    const float* bout_T = (const float*)d_in[8];
    const float* bias_T = (const float*)d_in[9];
    const float* bias_S = (const float*)d_in[10];
    float* out = (float*)d_out;

    constexpr int B = 16, T = 1024, N = 512, DKT = 64, DKS = 128;
    typedef unsigned short us;

    // ---- workspace layout (region reuse; peak ~146 MB, proven) ----
    char* w = (char*)d_ws;
    size_t off = 0;
    auto alloc = [&](size_t bytes) { char* p = w + off; off = (off + bytes + 255) & ~(size_t)255; return p; };
    us* wqkT_h = (us*)alloc(128 * 512 * 2);      // [128][512]: rows 0-63 Wq^T, 64-127 Wk^T
    us* wqkT_l = (us*)alloc(128 * 512 * 2);
    us* wvt_h  = (us*)alloc(512 * 512 * 2);      // Wv^T [512][512]
    us* wvt_l  = (us*)alloc(512 * 512 * 2);
    us* wqks_h = (us*)alloc(256 * 1024 * 2);     // rows 0-127 WqS^T, 128-255 WkS^T
    us* wqks_l = (us*)alloc(256 * 1024 * 2);
    us* wout_h = (us*)alloc(512 * 512 * 2);      // Wout^T
    us* wout_l = (us*)alloc(512 * 512 * 2);
    us* qk_h   = (us*)alloc((size_t)16384 * 128 * 2);  // temporal q|k; reused as spatial [8192][256]
    us* qk_l   = (us*)alloc((size_t)16384 * 128 * 2);
    float* attnT = (float*)alloc((size_t)B * T * T * 4); // logits fp32; P bf16 in place
    us* vT_h   = (us*)alloc((size_t)B * N * T * 2);      // v^T planes; reused as out2
    us* vT_l   = (us*)alloc((size_t)B * N * T * 2);
    us* outT_h = (us*)alloc((size_t)B * T * N * 2);
    us* outT_l = (us*)alloc((size_t)B * T * N * 2);
    float* attnS = attnT;          // [B][512][512] fp32, after attnT's last read
    us* out2_h = vT_h;             // after vT's last read
    us* out2_l = vT_l;

    const float scale_T = 0.125f;
    const float scale_S = 0.088388347648318447f;
    const int BIG = 1 << 30;

    // ---- weight transposes + splits ----
    dim3 tb(32, 8);
    transpose_split<<<dim3(2, 16),  tb, 0, stream>>>(Wq_T,   wqkT_h, wqkT_l, 512, 64,   0, 512);
    transpose_split<<<dim3(2, 16),  tb, 0, stream>>>(Wk_T,   wqkT_h, wqkT_l, 512, 64,  64, 512);
    transpose_split<<<dim3(16, 16), tb, 0, stream>>>(Wv_T,   wvt_h,  wvt_l,  512, 512,  0, 512);
    transpose_split<<<dim3(4, 32),  tb, 0, stream>>>(Wq_S,   wqks_h, wqks_l, 1024, 128, 0, 1024);
    transpose_split<<<dim3(4, 32),  tb, 0, stream>>>(Wk_S,   wqks_h, wqks_l, 1024, 128, 128, 1024);
    transpose_split<<<dim3(16, 16), tb, 0, stream>>>(Wout_T, wout_h, wout_l, 512, 512,  0, 512);

    // ---- temporal chain ----
    // qk = x_T @ [Wq|Wk]^T  (cols<64: *scale_T + bias_T)  [16384 x 128], K=512, 3-pass
    gemm_nt<64, 64, 1, 3, 2, true><<<dim3(2, 256, 1), 256, 0, stream>>>(
        x_T, nullptr, wqkT_h, wqkT_l, qk_h, qk_l, bias_T,
        512, 512, 512, 128, 0, 0, 0, scale_T, 64);
    // v^T_b = Wv^T @ x_b^T   [512 x 1024] per b, K=512, 3-pass
    gemm_nt<128, 128, 3, 1, 2, false><<<dim3(8, 4, B), 256, 0, stream>>>(
        wvt_h, wvt_l, x_T, nullptr, vT_h, vT_l, nullptr,
        512, 512, 512, 1024, 0, (long)T * N, (long)N * T, 1.0f, 0);
    // logits_T = q_b @ k_b^T  [1024 x 1024] per b, K=64, 3-pass, fp32 out
    gemm_nt<128, 128, 3, 3, 0, false><<<dim3(8, 8, B), 256, 0, stream>>>(
        qk_h, qk_l, qk_h + 64, qk_l + 64, attnT, nullptr, nullptr,
        64, 128, 128, 1024, (long)T * 128, (long)T * 128, (long)T * T, 1.0f, 0);
    // softmax -> P bf16 in place (row stride 2048 ushorts, first 1024 used)
    softmax_rows<1024, true><<<B * T, 256, 0, stream>>>(attnT);
    // outT = P_b @ v_b  (NT vs v^T)  [1024 x 512] per b, K=1024, 2-pass (P hi-only bf16)
    gemm_nt<128, 128, 2, 3, 2, false><<<dim3(4, 8, B), 256, 0, stream>>>(
        attnT, nullptr, vT_h, vT_l, outT_h, outT_l, nullptr,
        1024, 2048, 1024, 512, (long)T * 2048, (long)N * T, (long)T * N, 1.0f, 0);

    // ---- spatial chain (reuses qk region and attnT region) ----
    // qkS = x_S @ [WqS|WkS]^T  (cols<128: *scale_S + bias_S)  [8192 x 256], K=1024, 3-pass
    gemm_nt<64, 64, 1, 3, 2, true><<<dim3(4, 128, 1), 256, 0, stream>>>(
        x_S, nullptr, wqks_h, wqks_l, qk_h, qk_l, bias_S,
        1024, 1024, 1024, 256, 0, 0, 0, scale_S, 128);
    // logits_S = qS_b @ kS_b^T  [512 x 512] per b, K=128, 3-pass, fp32 out
    gemm_nt<64, 64, 3, 3, 0, false><<<dim3(8, 8, B), 256, 0, stream>>>(
        qk_h, qk_l, qk_h + 128, qk_l + 128, attnS, nullptr, nullptr,
        128, 256, 256, 512, (long)N * 256, (long)N * 256, (long)N * N, 1.0f, 0);
    // softmax -> P_S bf16 in place (row stride 1024 ushorts, first 512 used)
    softmax_rows<512, true><<<B * N, 256, 0, stream>>>(attnS);
    // out2 = outT_b @ P_S_b^T  [1024 x 512] per b, K=512, 2-pass (P_S hi-only bf16)
    gemm_nt<128, 128, 3, 2, 2, false><<<dim3(4, 8, B), 256, 0, stream>>>(
        outT_h, outT_l, attnS, nullptr, out2_h, out2_l, nullptr,
        512, 512, 1024, 512, (long)T * N, (long)N * 1024, (long)T * N, 1.0f, 0);
    // out[b,i,t] = (out2_b @ Wout + bout)^T  [512 x 1024] per b via STORE_T, K=512, 3-pass
    gemm_nt<128, 128, 3, 3, 1, true><<<dim3(4, 8, B), 256, 0, stream>>>(
        out2_h, out2_l, wout_h, wout_l, out, nullptr, bout_T,
        512, 512, 512, 1024, (long)T * N, 0, (long)N * T, 1.0f, BIG);
}

// Round 6
// 236.715 us; speedup vs baseline: 1.8201x; 1.1867x over previous
//
#include <hip/hip_runtime.h>
#include <cstddef>

typedef short short8 __attribute__((ext_vector_type(8)));
typedef unsigned short ushortx8 __attribute__((ext_vector_type(8)));
typedef float floatx4 __attribute__((ext_vector_type(4)));

__device__ __forceinline__ unsigned int bf16_rne(float x) {
    unsigned int u = __float_as_uint(x);
    return (u + 0x7fffu + ((u >> 16) & 1u)) >> 16;
}

__device__ __forceinline__ void split4(const floatx4 v,
                                       unsigned long long& hp,
                                       unsigned long long& lp) {
    unsigned int h[4], l[4];
    #pragma unroll
    for (int j = 0; j < 4; ++j) {
        h[j] = bf16_rne(v[j]);
        float hf = __uint_as_float(h[j] << 16);
        l[j] = bf16_rne(v[j] - hf);
    }
    hp = (unsigned long long)(h[0] | (h[1] << 16)) |
         ((unsigned long long)(h[2] | (h[3] << 16)) << 32);
    lp = (unsigned long long)(l[0] | (l[1] << 16)) |
         ((unsigned long long)(l[2] | (l[3] << 16)) << 32);
}

__device__ __forceinline__ unsigned long long pack_hi4(const floatx4 v) {
    unsigned int h0 = bf16_rne(v[0]), h1 = bf16_rne(v[1]);
    unsigned int h2 = bf16_rne(v[2]), h3 = bf16_rne(v[3]);
    return (unsigned long long)(h0 | (h1 << 16)) |
           ((unsigned long long)(h2 | (h3 << 16)) << 32);
}

// ---------------------------------------------------------------------------
// NT GEMM, software-pipelined (reg prefetch + LDS double-buffer, 1 barrier/step)
//   AMODE/BMODE: 0 = fp32 src, hi only; 1 = fp32 src, hi+lo;
//                2 = bf16 planes, hi only; 3 = bf16 planes, hi+lo
//   MFMA passes: Ah*Bh (+ Al*Bh if ALO) (+ Ah*Bl if BLO)
//   OUTMODE: 0 = fp32 row-major; 1 = fp32 transposed (float4 along m);
//            2 = bf16 hi+lo planes; 3 = bf16 hi plane only
//   Epilogue: for col gn < nsplit: val = acc*alpha + bias[gn]; else val = acc.
// Block = 256 threads = 4 waves (2x2), wave owns (BM/2)x(BN/2).
// lda/ldb/sA/sB in ELEMENTS of the source type (float or ushort).
// ---------------------------------------------------------------------------
template<int BM, int BN, int AMODE, int BMODE, int OUTMODE, bool HASBIAS>
__global__ __launch_bounds__(256, 2)
void gemm_nt(const void* __restrict__ Ah_, const void* __restrict__ Al_,
             const void* __restrict__ Bh_, const void* __restrict__ Bl_,
             void* __restrict__ C_, void* __restrict__ Cl_,
             const float* __restrict__ bias,
             int K, int lda, int ldb, int ldc,
             long sA, long sB, long sC, float alpha, int nsplit)
{
    constexpr bool ALO = (AMODE == 1 || AMODE == 3);
    constexpr bool BLO = (BMODE == 1 || BMODE == 3);
    constexpr int LS = 40;   // 32 + 8 pad halves -> 80B rows, 2-way bank alias (free)
    __shared__ unsigned short Ash[2][BM][LS];
    __shared__ unsigned short Als[2][ALO ? BM : 1][LS];
    __shared__ unsigned short Bsh[2][BN][LS];
    __shared__ unsigned short Bls[2][BLO ? BN : 1][LS];

    const int b   = blockIdx.z;
    const int bm0 = blockIdx.y * BM;
    const int bn0 = blockIdx.x * BN;
    const int tid  = threadIdx.x;
    const int lane = tid & 63;
    const int wid  = tid >> 6;
    const int wr = wid >> 1, wc = wid & 1;
    constexpr int WM = BM / 2, WN = BN / 2;
    constexpr int FM = WM / 16, FN = WN / 16;
    floatx4 acc[FM][FN] = {};
    const int l15  = lane & 15;
    const int koff = (lane >> 4) * 8;

    constexpr int NAF = (AMODE <= 1) ? (BM * 32) / 1024 : 1;
    constexpr int NAH = (AMODE >= 2) ? (BM * 32) / 2048 : 1;
    constexpr int NBF = (BMODE <= 1) ? (BN * 32) / 1024 : 1;
    constexpr int NBH = (BMODE >= 2) ? (BN * 32) / 2048 : 1;
    floatx4  aF[NAF], bF[NBF];
    ushortx8 aH[NAH], aL[NAH], bH[NBH], bL[NBH];

    auto loadA = [&](int k0) {
        if (AMODE <= 1) {
            const float* A = (const float*)Ah_ + (long)b * sA;
            #pragma unroll
            for (int i = 0; i < NAF; ++i) {
                int flat = i * 1024 + tid * 4;
                int r = flat >> 5, c = flat & 31;
                aF[i] = *(const floatx4*)(A + (long)(bm0 + r) * lda + k0 + c);
            }
        } else {
            const unsigned short* A  = (const unsigned short*)Ah_ + (long)b * sA;
            const unsigned short* Al = (const unsigned short*)Al_ + (long)b * sA;
            #pragma unroll
            for (int i = 0; i < NAH; ++i) {
                int flat = i * 2048 + tid * 8;
                int r = flat >> 5, c = flat & 31;
                aH[i] = *(const ushortx8*)(A + (long)(bm0 + r) * lda + k0 + c);
                if (AMODE == 3)
                    aL[i] = *(const ushortx8*)(Al + (long)(bm0 + r) * lda + k0 + c);
            }
        }
    };
    auto loadB = [&](int k0) {
        if (BMODE <= 1) {
            const float* Bp = (const float*)Bh_ + (long)b * sB;
            #pragma unroll
            for (int i = 0; i < NBF; ++i) {
                int flat = i * 1024 + tid * 4;
                int r = flat >> 5, c = flat & 31;
                bF[i] = *(const floatx4*)(Bp + (long)(bn0 + r) * ldb + k0 + c);
            }
        } else {
            const unsigned short* Bp = (const unsigned short*)Bh_ + (long)b * sB;
            const unsigned short* Bl = (const unsigned short*)Bl_ + (long)b * sB;
            #pragma unroll
            for (int i = 0; i < NBH; ++i) {
                int flat = i * 2048 + tid * 8;
                int r = flat >> 5, c = flat & 31;
                bH[i] = *(const ushortx8*)(Bp + (long)(bn0 + r) * ldb + k0 + c);
                if (BMODE == 3)
                    bL[i] = *(const ushortx8*)(Bl + (long)(bn0 + r) * ldb + k0 + c);
            }
        }
    };
    auto writeA = [&](int bf) {
        if (AMODE <= 1) {
            #pragma unroll
            for (int i = 0; i < NAF; ++i) {
                int flat = i * 1024 + tid * 4;
                int r = flat >> 5, c = flat & 31;
                if (AMODE == 1) {
                    unsigned long long hp, lp; split4(aF[i], hp, lp);
                    *(unsigned long long*)&Ash[bf][r][c] = hp;
                    *(unsigned long long*)&Als[bf][r][c] = lp;
                } else {
                    *(unsigned long long*)&Ash[bf][r][c] = pack_hi4(aF[i]);
                }
            }
        } else {
            #pragma unroll
            for (int i = 0; i < NAH; ++i) {
                int flat = i * 2048 + tid * 8;
                int r = flat >> 5, c = flat & 31;
                *(ushortx8*)&Ash[bf][r][c] = aH[i];
                if (AMODE == 3) *(ushortx8*)&Als[bf][r][c] = aL[i];
            }
        }
    };
    auto writeB = [&](int bf) {
        if (BMODE <= 1) {
            #pragma unroll
            for (int i = 0; i < NBF; ++i) {
                int flat = i * 1024 + tid * 4;
                int r = flat >> 5, c = flat & 31;
                if (BMODE == 1) {
                    unsigned long long hp, lp; split4(bF[i], hp, lp);
                    *(unsigned long long*)&Bsh[bf][r][c] = hp;
                    *(unsigned long long*)&Bls[bf][r][c] = lp;
                } else {
                    *(unsigned long long*)&Bsh[bf][r][c] = pack_hi4(bF[i]);
                }
            }
        } else {
            #pragma unroll
            for (int i = 0; i < NBH; ++i) {
                int flat = i * 2048 + tid * 8;
                int r = flat >> 5, c = flat & 31;
                *(ushortx8*)&Bsh[bf][r][c] = bH[i];
                if (BMODE == 3) *(ushortx8*)&Bls[bf][r][c] = bL[i];
            }
        }
    };
    auto compute = [&](int bf) {
        short8 ah[FM], al[FM], bh[FN], bl[FN];
        #pragma unroll
        for (int mi = 0; mi < FM; ++mi) {
            ah[mi] = *(const short8*)&Ash[bf][wr * WM + mi * 16 + l15][koff];
            if (ALO) al[mi] = *(const short8*)&Als[bf][wr * WM + mi * 16 + l15][koff];
        }
        #pragma unroll
        for (int ni = 0; ni < FN; ++ni) {
            bh[ni] = *(const short8*)&Bsh[bf][wc * WN + ni * 16 + l15][koff];
            if (BLO) bl[ni] = *(const short8*)&Bls[bf][wc * WN + ni * 16 + l15][koff];
        }
        #pragma unroll
        for (int mi = 0; mi < FM; ++mi)
            #pragma unroll
            for (int ni = 0; ni < FN; ++ni) {
                if (ALO)
                    acc[mi][ni] = __builtin_amdgcn_mfma_f32_16x16x32_bf16(
                        al[mi], bh[ni], acc[mi][ni], 0, 0, 0);
                if (BLO)
                    acc[mi][ni] = __builtin_amdgcn_mfma_f32_16x16x32_bf16(
                        ah[mi], bl[ni], acc[mi][ni], 0, 0, 0);
                acc[mi][ni] = __builtin_amdgcn_mfma_f32_16x16x32_bf16(
                    ah[mi], bh[ni], acc[mi][ni], 0, 0, 0);
            }
    };

    loadA(0); loadB(0);
    writeA(0); writeB(0);
    __syncthreads();
    int cur = 0;
    for (int k0 = 32; k0 < K; k0 += 32) {
        loadA(k0); loadB(k0);
        compute(cur);
        writeA(cur ^ 1); writeB(cur ^ 1);
        __syncthreads();
        cur ^= 1;
    }
    compute(cur);

    const int rq = (lane >> 4) * 4;
    #pragma unroll
    for (int mi = 0; mi < FM; ++mi) {
        #pragma unroll
        for (int ni = 0; ni < FN; ++ni) {
            int gm = bm0 + wr * WM + mi * 16 + rq;
            int gn = bn0 + wc * WN + ni * 16 + l15;
            float ae = (gn < nsplit) ? alpha : 1.0f;
            float be = 0.f;
            if (HASBIAS) be = (gn < nsplit) ? bias[gn] : 0.0f;
            float vals[4];
            #pragma unroll
            for (int j = 0; j < 4; ++j) vals[j] = acc[mi][ni][j] * ae + be;
            if (OUTMODE == 0) {
                float* C = (float*)C_ + (long)b * sC;
                #pragma unroll
                for (int j = 0; j < 4; ++j) C[(long)(gm + j) * ldc + gn] = vals[j];
            } else if (OUTMODE == 1) {
                float* C = (float*)C_ + (long)b * sC;
                floatx4 o;
                #pragma unroll
                for (int j = 0; j < 4; ++j) o[j] = vals[j];
                *(floatx4*)(C + (long)gn * ldc + gm) = o;
            } else if (OUTMODE == 2) {
                unsigned short* Ch = (unsigned short*)C_ + (long)b * sC;
                unsigned short* Cl = (unsigned short*)Cl_ + (long)b * sC;
                #pragma unroll
                for (int j = 0; j < 4; ++j) {
                    unsigned int h = bf16_rne(vals[j]);
                    float hf = __uint_as_float(h << 16);
                    unsigned int lo = bf16_rne(vals[j] - hf);
                    Ch[(long)(gm + j) * ldc + gn] = (unsigned short)h;
                    Cl[(long)(gm + j) * ldc + gn] = (unsigned short)lo;
                }
            } else {
                unsigned short* Ch = (unsigned short*)C_ + (long)b * sC;
                #pragma unroll
                for (int j = 0; j < 4; ++j)
                    Ch[(long)(gm + j) * ldc + gn] = (unsigned short)bf16_rne(vals[j]);
            }
        }
    }
}

// ---------------------------------------------------------------------------
// Fused QK^T + row softmax -> P (bf16), per 32-row q-tile.
// qk planes: [rows][LDQK] with q at cols [0,DK), k at cols [DK,2*DK).
// Block 256 thr = 4 waves; wave w owns logit cols [w*COLS/4, (w+1)*COLS/4).
// q tile staged in LDS (hi+lo); k fragments read direct from global (L2-hot).
// 3-pass MFMA (fp32-grade logits). Output P[b][row][col] bf16 row-major.
// Grid: (COLS/32, B).   batch rows in qk planes = COLS.
// ---------------------------------------------------------------------------
template<int COLS, int DK, int LDQK>
__global__ __launch_bounds__(256, 2)
void qk_softmax(const unsigned short* __restrict__ qk_h,
                const unsigned short* __restrict__ qk_l,
                unsigned short* __restrict__ P)
{
    constexpr int WCOLS = COLS / 4;
    constexpr int FN = WCOLS / 16;
    constexpr int QPAD = DK + 24;     // rows 16B-aligned, 2-way bank alias (free)
    __shared__ unsigned short Qh[32][QPAD];
    __shared__ unsigned short Ql[32][QPAD];
    __shared__ float red[32][4];
    __shared__ unsigned short Pl[32][COLS + 8];

    const int b  = blockIdx.y;
    const int q0 = blockIdx.x * 32;
    const long rowBase = (long)b * COLS;
    const int tid = threadIdx.x;
    const int lane = tid & 63, wid = tid >> 6;
    const int l15 = lane & 15, g = lane >> 4;
    const int koff = g * 8;

    // stage q tile (32 x DK, hi+lo)
    constexpr int QCH = DK / 8;
    for (int i = tid; i < 32 * QCH; i += 256) {
        int r = i / QCH, c = (i % QCH) * 8;
        *(ushortx8*)&Qh[r][c] = *(const ushortx8*)(qk_h + (rowBase + q0 + r) * LDQK + c);
        *(ushortx8*)&Ql[r][c] = *(const ushortx8*)(qk_l + (rowBase + q0 + r) * LDQK + c);
    }
    __syncthreads();

    floatx4 acc[2][FN] = {};
    const unsigned short* kh = qk_h + rowBase * LDQK + DK;
    const unsigned short* kl = qk_l + rowBase * LDQK + DK;

    #pragma unroll
    for (int kk = 0; kk < DK; kk += 32) {
        short8 ah[2], al[2];
        #pragma unroll
        for (int mi = 0; mi < 2; ++mi) {
            ah[mi] = *(const short8*)&Qh[mi * 16 + l15][kk + koff];
            al[mi] = *(const short8*)&Ql[mi * 16 + l15][kk + koff];
        }
        #pragma unroll
        for (int ni = 0; ni < FN; ++ni) {
            long krow = wid * WCOLS + ni * 16 + l15;
            short8 bh = *(const short8*)(kh + krow * LDQK + kk + koff);
            short8 bl = *(const short8*)(kl + krow * LDQK + kk + koff);
            #pragma unroll
            for (int mi = 0; mi < 2; ++mi) {
                acc[mi][ni] = __builtin_amdgcn_mfma_f32_16x16x32_bf16(al[mi], bh, acc[mi][ni], 0, 0, 0);
                acc[mi][ni] = __builtin_amdgcn_mfma_f32_16x16x32_bf16(ah[mi], bl, acc[mi][ni], 0, 0, 0);
                acc[mi][ni] = __builtin_amdgcn_mfma_f32_16x16x32_bf16(ah[mi], bh, acc[mi][ni], 0, 0, 0);
            }
        }
    }

    // ---- row softmax (rows: mi*16 + g*4 + j) ----
    float pm[2][4];
    #pragma unroll
    for (int mi = 0; mi < 2; ++mi)
        #pragma unroll
        for (int j = 0; j < 4; ++j) {
            float m = acc[mi][0][j];
            #pragma unroll
            for (int ni = 1; ni < FN; ++ni) m = fmaxf(m, acc[mi][ni][j]);
            pm[mi][j] = m;
        }
    #pragma unroll
    for (int msk = 1; msk < 16; msk <<= 1) {
        #pragma unroll
        for (int mi = 0; mi < 2; ++mi)
            #pragma unroll
            for (int j = 0; j < 4; ++j)
                pm[mi][j] = fmaxf(pm[mi][j], __shfl_xor(pm[mi][j], msk));
    }
    if (l15 == 0) {
        #pragma unroll
        for (int mi = 0; mi < 2; ++mi)
            #pragma unroll
            for (int j = 0; j < 4; ++j) red[mi * 16 + g * 4 + j][wid] = pm[mi][j];
    }
    __syncthreads();
    float rm[2][4];
    #pragma unroll
    for (int mi = 0; mi < 2; ++mi)
        #pragma unroll
        for (int j = 0; j < 4; ++j) {
            const float* r4 = red[mi * 16 + g * 4 + j];
            rm[mi][j] = fmaxf(fmaxf(r4[0], r4[1]), fmaxf(r4[2], r4[3]));
        }
    __syncthreads();   // protect red before reuse for sums

    float ps[2][4] = {};
    #pragma unroll
    for (int mi = 0; mi < 2; ++mi)
        #pragma unroll
        for (int ni = 0; ni < FN; ++ni)
            #pragma unroll
            for (int j = 0; j < 4; ++j) {
                float e = __expf(acc[mi][ni][j] - rm[mi][j]);
                acc[mi][ni][j] = e;
                ps[mi][j] += e;
            }
    #pragma unroll
    for (int msk = 1; msk < 16; msk <<= 1) {
        #pragma unroll
        for (int mi = 0; mi < 2; ++mi)
            #pragma unroll
            for (int j = 0; j < 4; ++j)
                ps[mi][j] += __shfl_xor(ps[mi][j], msk);
    }
    if (l15 == 0) {
        #pragma unroll
        for (int mi = 0; mi < 2; ++mi)
            #pragma unroll
            for (int j = 0; j < 4; ++j) red[mi * 16 + g * 4 + j][wid] = ps[mi][j];
    }
    __syncthreads();
    float inv[2][4];
    #pragma unroll
    for (int mi = 0; mi < 2; ++mi)
        #pragma unroll
        for (int j = 0; j < 4; ++j) {
            const float* r4 = red[mi * 16 + g * 4 + j];
            inv[mi][j] = 1.0f / (r4[0] + r4[1] + r4[2] + r4[3]);
        }

    // write P tile to LDS (transpose from fragment layout to row-major)
    #pragma unroll
    for (int mi = 0; mi < 2; ++mi)
        #pragma unroll
        for (int ni = 0; ni < FN; ++ni)
            #pragma unroll
            for (int j = 0; j < 4; ++j)
                Pl[mi * 16 + g * 4 + j][wid * WCOLS + ni * 16 + l15] =
                    (unsigned short)bf16_rne(acc[mi][ni][j] * inv[mi][j]);
    __syncthreads();

    // coalesced copy out
    constexpr int PCH = COLS / 8;
    for (int i = tid; i < 32 * PCH; i += 256) {
        int r = i / PCH, c = (i % PCH) * 8;
        *(ushortx8*)(P + (rowBase + q0 + r) * COLS + c) = *(const ushortx8*)&Pl[r][c];
    }
}

// ---------------------------------------------------------------------------
// Transpose + split: in[R][C] fp32 -> outH/outL[(c+rowOff)][r] bf16 planes
// ---------------------------------------------------------------------------
__global__ __launch_bounds__(256)
void transpose_split(const float* __restrict__ in,
                     unsigned short* __restrict__ outH,
                     unsigned short* __restrict__ outL,
                     int R, int C, int rowOff, int ldo)
{
    __shared__ float tile[32][33];
    const int tc = blockIdx.x * 32, tr = blockIdx.y * 32;
    const int x = threadIdx.x, y = threadIdx.y;
    #pragma unroll
    for (int i = 0; i < 32; i += 8)
        tile[y + i][x] = in[(long)(tr + y + i) * C + tc + x];
    __syncthreads();
    #pragma unroll
    for (int i = 0; i < 32; i += 8) {
        float v = tile[x][y + i];
        unsigned int h = bf16_rne(v);
        float hf = __uint_as_float(h << 16);
        unsigned int lo = bf16_rne(v - hf);
        long idx = (long)(tc + y + i + rowOff) * ldo + tr + x;
        outH[idx] = (unsigned short)h;
        outL[idx] = (unsigned short)lo;
    }
}

extern "C" void kernel_launch(void* const* d_in, const int* in_sizes, int n_in,
                              void* d_out, int out_size, void* d_ws, size_t ws_size,
                              hipStream_t stream)
{
    (void)in_sizes; (void)n_in; (void)out_size; (void)ws_size;
    const float* x_T    = (const float*)d_in[0];
    const float* x_S    = (const float*)d_in[1];
    const float* Wq_T   = (const float*)d_in[2];
    const float* Wk_T   = (const float*)d_in[3];
    const float* Wv_T   = (const float*)d_in[4];
    const float* Wq_S   = (const float*)d_in[5];
    const float* Wk_S   = (const float*)d_in[6];
    const float* Wout_T = (const float*)d_in[7];
    const float* bout_T = (const float*)d_in[8];
    const float* bias_T = (const float*)d_in[9];
    const float* bias_S = (const float*)d_in[10];
    float* out = (float*)d_out;

    constexpr int B = 16, T = 1024, N = 512, DKT = 64, DKS = 128;
    typedef unsigned short us;

    char* w = (char*)d_ws;
    size_t off = 0;
    auto alloc = [&](size_t bytes) { char* p = w + off; off = (off + bytes + 255) & ~(size_t)255; return p; };
    us* wqkT_h = (us*)alloc(128 * 512 * 2);
    us* wqkT_l = (us*)alloc(128 * 512 * 2);
    us* wvt_h  = (us*)alloc(512 * 512 * 2);
    us* wvt_l  = (us*)alloc(512 * 512 * 2);
    us* wqks_h = (us*)alloc(256 * 1024 * 2);
    us* wqks_l = (us*)alloc(256 * 1024 * 2);
    us* wout_h = (us*)alloc(512 * 512 * 2);
    us* wout_l = (us*)alloc(512 * 512 * 2);
    us* qk_h   = (us*)alloc((size_t)16384 * 128 * 2);  // temporal q|k; spatial [8192][256]
    us* qk_l   = (us*)alloc((size_t)16384 * 128 * 2);
    us* P_T    = (us*)alloc((size_t)B * T * T * 2);    // 32 MB
    us* P_S    = (us*)alloc((size_t)B * N * N * 2);    // 8 MB
    us* vT_h   = (us*)alloc((size_t)B * N * T * 2);    // v^T hi; reused as out2_h
    us* vT_l   = (us*)alloc((size_t)B * N * T * 2);    // unused by vT now; reused as out2_l
    us* outT_h = (us*)alloc((size_t)B * T * N * 2);
    us* outT_l = (us*)alloc((size_t)B * T * N * 2);
    us* out2_h = vT_h;
    us* out2_l = vT_l;

    const float scale_T = 0.125f;
    const float scale_S = 0.088388347648318447f;
    const int BIG = 1 << 30;

    dim3 tb(32, 8);
    transpose_split<<<dim3(2, 16),  tb, 0, stream>>>(Wq_T,   wqkT_h, wqkT_l, 512, 64,   0, 512);
    transpose_split<<<dim3(2, 16),  tb, 0, stream>>>(Wk_T,   wqkT_h, wqkT_l, 512, 64,  64, 512);
    transpose_split<<<dim3(16, 16), tb, 0, stream>>>(Wv_T,   wvt_h,  wvt_l,  512, 512,  0, 512);
    transpose_split<<<dim3(4, 32),  tb, 0, stream>>>(Wq_S,   wqks_h, wqks_l, 1024, 128, 0, 1024);
    transpose_split<<<dim3(4, 32),  tb, 0, stream>>>(Wk_S,   wqks_h, wqks_l, 1024, 128, 128, 1024);
    transpose_split<<<dim3(16, 16), tb, 0, stream>>>(Wout_T, wout_h, wout_l, 512, 512,  0, 512);

    // ---- temporal chain ----
    // qk = x_T @ [Wq|Wk]^T (cols<64: *scale_T + bias_T)  [16384 x 128], K=512, 3-pass
    gemm_nt<64, 64, 1, 3, 2, true><<<dim3(2, 256, 1), 256, 0, stream>>>(
        x_T, nullptr, wqkT_h, wqkT_l, qk_h, qk_l, bias_T,
        512, 512, 512, 128, 0, 0, 0, scale_T, 64);
    // v^T_b = Wv^T @ x_b^T  [512 x 1024] per b, K=512, 2-pass, hi-only out
    gemm_nt<128, 128, 3, 0, 3, false><<<dim3(8, 4, B), 256, 0, stream>>>(
        wvt_h, wvt_l, x_T, nullptr, vT_h, nullptr, nullptr,
        512, 512, 512, 1024, 0, (long)T * N, (long)N * T, 1.0f, 0);
    // fused logits_T + softmax -> P_T bf16  [per b: 1024 x 1024]
    qk_softmax<1024, 64, 128><<<dim3(32, 16), 256, 0, stream>>>(qk_h, qk_l, P_T);
    // outT = P_T @ v  (NT vs v^T)  [1024 x 512] per b, K=1024, 1-pass (P-hi x v-hi)
    gemm_nt<128, 128, 2, 2, 2, false><<<dim3(4, 8, B), 256, 0, stream>>>(
        P_T, nullptr, vT_h, nullptr, outT_h, outT_l, nullptr,
        1024, 1024, 1024, 512, (long)T * T, (long)N * T, (long)T * N, 1.0f, 0);

    // ---- spatial chain ----
    // qkS = x_S @ [WqS|WkS]^T (cols<128: *scale_S + bias_S)  [8192 x 256], K=1024, 3-pass
    gemm_nt<64, 64, 1, 3, 2, true><<<dim3(4, 128, 1), 256, 0, stream>>>(
        x_S, nullptr, wqks_h, wqks_l, qk_h, qk_l, bias_S,
        1024, 1024, 1024, 256, 0, 0, 0, scale_S, 128);
    // fused logits_S + softmax -> P_S bf16  [per b: 512 x 512]
    qk_softmax<512, 128, 256><<<dim3(16, 16), 256, 0, stream>>>(qk_h, qk_l, P_S);
    // out2 = outT_b @ P_S_b^T  [1024 x 512] per b, K=512, 2-pass
    gemm_nt<128, 128, 3, 2, 2, false><<<dim3(4, 8, B), 256, 0, stream>>>(
        outT_h, outT_l, P_S, nullptr, out2_h, out2_l, nullptr,
        512, 512, 512, 512, (long)T * N, (long)N * N, (long)T * N, 1.0f, 0);
    // out[b,i,t] = (out2_b @ Wout + bout)^T  [512 x 1024] per b, K=512, 2-pass
    gemm_nt<128, 128, 3, 2, 1, true><<<dim3(4, 8, B), 256, 0, stream>>>(
        out2_h, out2_l, wout_h, nullptr, out, nullptr, bout_T,
        512, 512, 512, 1024, (long)T * N, 0, (long)N * T, 1.0f, BIG);
}

// Round 7
// 221.766 us; speedup vs baseline: 1.9428x; 1.0674x over previous
//
#include <hip/hip_runtime.h>
#include <cstddef>

typedef short short8 __attribute__((ext_vector_type(8)));
typedef unsigned short ushortx8 __attribute__((ext_vector_type(8)));
typedef float floatx4 __attribute__((ext_vector_type(4)));

__device__ __forceinline__ unsigned int bf16_rne(float x) {
    unsigned int u = __float_as_uint(x);
    return (u + 0x7fffu + ((u >> 16) & 1u)) >> 16;
}

__device__ __forceinline__ void split4(const floatx4 v,
                                       unsigned long long& hp,
                                       unsigned long long& lp) {
    unsigned int h[4], l[4];
    #pragma unroll
    for (int j = 0; j < 4; ++j) {
        h[j] = bf16_rne(v[j]);
        float hf = __uint_as_float(h[j] << 16);
        l[j] = bf16_rne(v[j] - hf);
    }
    hp = (unsigned long long)(h[0] | (h[1] << 16)) |
         ((unsigned long long)(h[2] | (h[3] << 16)) << 32);
    lp = (unsigned long long)(l[0] | (l[1] << 16)) |
         ((unsigned long long)(l[2] | (l[3] << 16)) << 32);
}

__device__ __forceinline__ unsigned long long pack_hi4(const floatx4 v) {
    unsigned int h0 = bf16_rne(v[0]), h1 = bf16_rne(v[1]);
    unsigned int h2 = bf16_rne(v[2]), h3 = bf16_rne(v[3]);
    return (unsigned long long)(h0 | (h1 << 16)) |
           ((unsigned long long)(h2 | (h3 << 16)) << 32);
}

// ---------------------------------------------------------------------------
// NT GEMM, software-pipelined (reg prefetch + LDS double-buffer, 1 barrier/step)
// with bijective XCD-chunked blockIdx swizzle (same-XCD blocks share L2 panels).
//   AMODE/BMODE: 0 = fp32 src, hi only; 1 = fp32 src, hi+lo;
//                2 = bf16 planes, hi only; 3 = bf16 planes, hi+lo
//   MFMA passes: Ah*Bh (+ Al*Bh if ALO) (+ Ah*Bl if BLO)
//   OUTMODE: 0 = fp32 row-major; 1 = fp32 transposed (float4 along m);
//            2 = bf16 hi+lo planes; 3 = bf16 hi plane only
//   Epilogue: for col gn < nsplit: val = acc*alpha + bias[gn]; else val = acc.
// Block = 256 threads = 4 waves (2x2), wave owns (BM/2)x(BN/2).
// lda/ldb/sA/sB in ELEMENTS of the source type (float or ushort).
// ---------------------------------------------------------------------------
template<int BM, int BN, int AMODE, int BMODE, int OUTMODE, bool HASBIAS>
__global__ __launch_bounds__(256, 2)
void gemm_nt(const void* __restrict__ Ah_, const void* __restrict__ Al_,
             const void* __restrict__ Bh_, const void* __restrict__ Bl_,
             void* __restrict__ C_, void* __restrict__ Cl_,
             const float* __restrict__ bias,
             int K, int lda, int ldb, int ldc,
             long sA, long sB, long sC, float alpha, int nsplit)
{
    constexpr bool ALO = (AMODE == 1 || AMODE == 3);
    constexpr bool BLO = (BMODE == 1 || BMODE == 3);
    constexpr int LS = 40;   // 32 + 8 pad halves -> 80B rows, 2-way bank alias (free)
    __shared__ unsigned short Ash[2][BM][LS];
    __shared__ unsigned short Als[2][ALO ? BM : 1][LS];
    __shared__ unsigned short Bsh[2][BN][LS];
    __shared__ unsigned short Bls[2][BLO ? BN : 1][LS];

    // bijective XCD-chunked swizzle (m204): same-XCD blocks get contiguous work
    const unsigned int gx = gridDim.x;
    const unsigned int nwg = gx * gridDim.y;
    unsigned int flat = blockIdx.y * gx + blockIdx.x;
    {
        unsigned int qq = nwg >> 3, rr = nwg & 7;
        unsigned int xcd = flat & 7, idx = flat >> 3;
        flat = (xcd < rr) ? (xcd * (qq + 1) + idx)
                          : (rr * (qq + 1) + (xcd - rr) * qq + idx);
    }
    const int b   = blockIdx.z;
    const int bm0 = (flat / gx) * BM;
    const int bn0 = (flat % gx) * BN;
    const int tid  = threadIdx.x;
    const int lane = tid & 63;
    const int wid  = tid >> 6;
    const int wr = wid >> 1, wc = wid & 1;
    constexpr int WM = BM / 2, WN = BN / 2;
    constexpr int FM = WM / 16, FN = WN / 16;
    floatx4 acc[FM][FN] = {};
    const int l15  = lane & 15;
    const int koff = (lane >> 4) * 8;

    // chunked staging: fp32 path = float4 chunks, bf16 path = ushort8 chunks
    constexpr int ACHF = BM * 32 / 4, NAF0 = (ACHF + 255) / 256;
    constexpr int ACHH = BM * 32 / 8, NAH0 = (ACHH + 255) / 256;
    constexpr int BCHF = BN * 32 / 4, NBF0 = (BCHF + 255) / 256;
    constexpr int BCHH = BN * 32 / 8, NBH0 = (BCHH + 255) / 256;
    constexpr int NAF = (AMODE <= 1) ? NAF0 : 1;
    constexpr int NAH = (AMODE >= 2) ? NAH0 : 1;
    constexpr int NBF = (BMODE <= 1) ? NBF0 : 1;
    constexpr int NBH = (BMODE >= 2) ? NBH0 : 1;
    floatx4  aF[NAF], bF[NBF];
    ushortx8 aH[NAH], aL[NAH], bH[NBH], bL[NBH];

    auto loadA = [&](int k0) {
        if (AMODE <= 1) {
            const float* A = (const float*)Ah_ + (long)b * sA;
            #pragma unroll
            for (int i = 0; i < NAF; ++i) {
                int idx = i * 256 + tid;
                if (ACHF % 256 == 0 || idx < ACHF) {
                    int flatc = idx * 4;
                    int r = flatc >> 5, c = flatc & 31;
                    aF[i] = *(const floatx4*)(A + (long)(bm0 + r) * lda + k0 + c);
                }
            }
        } else {
            const unsigned short* A  = (const unsigned short*)Ah_ + (long)b * sA;
            const unsigned short* Al = (const unsigned short*)Al_ + (long)b * sA;
            #pragma unroll
            for (int i = 0; i < NAH; ++i) {
                int idx = i * 256 + tid;
                if (ACHH % 256 == 0 || idx < ACHH) {
                    int flatc = idx * 8;
                    int r = flatc >> 5, c = flatc & 31;
                    aH[i] = *(const ushortx8*)(A + (long)(bm0 + r) * lda + k0 + c);
                    if (AMODE == 3)
                        aL[i] = *(const ushortx8*)(Al + (long)(bm0 + r) * lda + k0 + c);
                }
            }
        }
    };
    auto loadB = [&](int k0) {
        if (BMODE <= 1) {
            const float* Bp = (const float*)Bh_ + (long)b * sB;
            #pragma unroll
            for (int i = 0; i < NBF; ++i) {
                int idx = i * 256 + tid;
                if (BCHF % 256 == 0 || idx < BCHF) {
                    int flatc = idx * 4;
                    int r = flatc >> 5, c = flatc & 31;
                    bF[i] = *(const floatx4*)(Bp + (long)(bn0 + r) * ldb + k0 + c);
                }
            }
        } else {
            const unsigned short* Bp = (const unsigned short*)Bh_ + (long)b * sB;
            const unsigned short* Bl = (const unsigned short*)Bl_ + (long)b * sB;
            #pragma unroll
            for (int i = 0; i < NBH; ++i) {
                int idx = i * 256 + tid;
                if (BCHH % 256 == 0 || idx < BCHH) {
                    int flatc = idx * 8;
                    int r = flatc >> 5, c = flatc & 31;
                    bH[i] = *(const ushortx8*)(Bp + (long)(bn0 + r) * ldb + k0 + c);
                    if (BMODE == 3)
                        bL[i] = *(const ushortx8*)(Bl + (long)(bn0 + r) * ldb + k0 + c);
                }
            }
        }
    };
    auto writeA = [&](int bf) {
        if (AMODE <= 1) {
            #pragma unroll
            for (int i = 0; i < NAF; ++i) {
                int idx = i * 256 + tid;
                if (ACHF % 256 == 0 || idx < ACHF) {
                    int flatc = idx * 4;
                    int r = flatc >> 5, c = flatc & 31;
                    if (AMODE == 1) {
                        unsigned long long hp, lp; split4(aF[i], hp, lp);
                        *(unsigned long long*)&Ash[bf][r][c] = hp;
                        *(unsigned long long*)&Als[bf][r][c] = lp;
                    } else {
                        *(unsigned long long*)&Ash[bf][r][c] = pack_hi4(aF[i]);
                    }
                }
            }
        } else {
            #pragma unroll
            for (int i = 0; i < NAH; ++i) {
                int idx = i * 256 + tid;
                if (ACHH % 256 == 0 || idx < ACHH) {
                    int flatc = idx * 8;
                    int r = flatc >> 5, c = flatc & 31;
                    *(ushortx8*)&Ash[bf][r][c] = aH[i];
                    if (AMODE == 3) *(ushortx8*)&Als[bf][r][c] = aL[i];
                }
            }
        }
    };
    auto writeB = [&](int bf) {
        if (BMODE <= 1) {
            #pragma unroll
            for (int i = 0; i < NBF; ++i) {
                int idx = i * 256 + tid;
                if (BCHF % 256 == 0 || idx < BCHF) {
                    int flatc = idx * 4;
                    int r = flatc >> 5, c = flatc & 31;
                    if (BMODE == 1) {
                        unsigned long long hp, lp; split4(bF[i], hp, lp);
                        *(unsigned long long*)&Bsh[bf][r][c] = hp;
                        *(unsigned long long*)&Bls[bf][r][c] = lp;
                    } else {
                        *(unsigned long long*)&Bsh[bf][r][c] = pack_hi4(bF[i]);
                    }
                }
            }
        } else {
            #pragma unroll
            for (int i = 0; i < NBH; ++i) {
                int idx = i * 256 + tid;
                if (BCHH % 256 == 0 || idx < BCHH) {
                    int flatc = idx * 8;
                    int r = flatc >> 5, c = flatc & 31;
                    *(ushortx8*)&Bsh[bf][r][c] = bH[i];
                    if (BMODE == 3) *(ushortx8*)&Bls[bf][r][c] = bL[i];
                }
            }
        }
    };
    auto compute = [&](int bf) {
        short8 ah[FM], al[FM], bh[FN], bl[FN];
        #pragma unroll
        for (int mi = 0; mi < FM; ++mi) {
            ah[mi] = *(const short8*)&Ash[bf][wr * WM + mi * 16 + l15][koff];
            if (ALO) al[mi] = *(const short8*)&Als[bf][wr * WM + mi * 16 + l15][koff];
        }
        #pragma unroll
        for (int ni = 0; ni < FN; ++ni) {
            bh[ni] = *(const short8*)&Bsh[bf][wc * WN + ni * 16 + l15][koff];
            if (BLO) bl[ni] = *(const short8*)&Bls[bf][wc * WN + ni * 16 + l15][koff];
        }
        #pragma unroll
        for (int mi = 0; mi < FM; ++mi)
            #pragma unroll
            for (int ni = 0; ni < FN; ++ni) {
                if (ALO)
                    acc[mi][ni] = __builtin_amdgcn_mfma_f32_16x16x32_bf16(
                        al[mi], bh[ni], acc[mi][ni], 0, 0, 0);
                if (BLO)
                    acc[mi][ni] = __builtin_amdgcn_mfma_f32_16x16x32_bf16(
                        ah[mi], bl[ni], acc[mi][ni], 0, 0, 0);
                acc[mi][ni] = __builtin_amdgcn_mfma_f32_16x16x32_bf16(
                    ah[mi], bh[ni], acc[mi][ni], 0, 0, 0);
            }
    };

    loadA(0); loadB(0);
    writeA(0); writeB(0);
    __syncthreads();
    int cur = 0;
    for (int k0 = 32; k0 < K; k0 += 32) {
        loadA(k0); loadB(k0);
        compute(cur);
        writeA(cur ^ 1); writeB(cur ^ 1);
        __syncthreads();
        cur ^= 1;
    }
    compute(cur);

    const int rq = (lane >> 4) * 4;
    #pragma unroll
    for (int mi = 0; mi < FM; ++mi) {
        #pragma unroll
        for (int ni = 0; ni < FN; ++ni) {
            int gm = bm0 + wr * WM + mi * 16 + rq;
            int gn = bn0 + wc * WN + ni * 16 + l15;
            float ae = (gn < nsplit) ? alpha : 1.0f;
            float be = 0.f;
            if (HASBIAS) be = (gn < nsplit) ? bias[gn] : 0.0f;
            float vals[4];
            #pragma unroll
            for (int j = 0; j < 4; ++j) vals[j] = acc[mi][ni][j] * ae + be;
            if (OUTMODE == 0) {
                float* C = (float*)C_ + (long)b * sC;
                #pragma unroll
                for (int j = 0; j < 4; ++j) C[(long)(gm + j) * ldc + gn] = vals[j];
            } else if (OUTMODE == 1) {
                float* C = (float*)C_ + (long)b * sC;
                floatx4 o;
                #pragma unroll
                for (int j = 0; j < 4; ++j) o[j] = vals[j];
                *(floatx4*)(C + (long)gn * ldc + gm) = o;
            } else if (OUTMODE == 2) {
                unsigned short* Ch = (unsigned short*)C_ + (long)b * sC;
                unsigned short* Cl = (unsigned short*)Cl_ + (long)b * sC;
                #pragma unroll
                for (int j = 0; j < 4; ++j) {
                    unsigned int h = bf16_rne(vals[j]);
                    float hf = __uint_as_float(h << 16);
                    unsigned int lo = bf16_rne(vals[j] - hf);
                    Ch[(long)(gm + j) * ldc + gn] = (unsigned short)h;
                    Cl[(long)(gm + j) * ldc + gn] = (unsigned short)lo;
                }
            } else {
                unsigned short* Ch = (unsigned short*)C_ + (long)b * sC;
                #pragma unroll
                for (int j = 0; j < 4; ++j)
                    Ch[(long)(gm + j) * ldc + gn] = (unsigned short)bf16_rne(vals[j]);
            }
        }
    }
}

// ---------------------------------------------------------------------------
// Fused QK^T + row softmax -> P (bf16), per 32-row q-tile.
// qk planes: [rows][LDQK] with q at cols [0,DK), k at cols [DK,2*DK).
// 3-pass MFMA (fp32-grade logits). Output P[b][row][col] bf16 row-major.
// Grid: (COLS/32, B).
// ---------------------------------------------------------------------------
template<int COLS, int DK, int LDQK>
__global__ __launch_bounds__(256, 2)
void qk_softmax(const unsigned short* __restrict__ qk_h,
                const unsigned short* __restrict__ qk_l,
                unsigned short* __restrict__ P)
{
    constexpr int WCOLS = COLS / 4;
    constexpr int FN = WCOLS / 16;
    constexpr int QPAD = DK + 24;
    __shared__ unsigned short Qh[32][QPAD];
    __shared__ unsigned short Ql[32][QPAD];
    __shared__ float red[32][4];
    __shared__ unsigned short Pl[32][COLS + 8];

    const int b  = blockIdx.y;
    const int q0 = blockIdx.x * 32;
    const long rowBase = (long)b * COLS;
    const int tid = threadIdx.x;
    const int lane = tid & 63, wid = tid >> 6;
    const int l15 = lane & 15, g = lane >> 4;
    const int koff = g * 8;

    constexpr int QCH = DK / 8;
    for (int i = tid; i < 32 * QCH; i += 256) {
        int r = i / QCH, c = (i % QCH) * 8;
        *(ushortx8*)&Qh[r][c] = *(const ushortx8*)(qk_h + (rowBase + q0 + r) * LDQK + c);
        *(ushortx8*)&Ql[r][c] = *(const ushortx8*)(qk_l + (rowBase + q0 + r) * LDQK + c);
    }
    __syncthreads();

    floatx4 acc[2][FN] = {};
    const unsigned short* kh = qk_h + rowBase * LDQK + DK;
    const unsigned short* kl = qk_l + rowBase * LDQK + DK;

    #pragma unroll
    for (int kk = 0; kk < DK; kk += 32) {
        short8 ah[2], al[2];
        #pragma unroll
        for (int mi = 0; mi < 2; ++mi) {
            ah[mi] = *(const short8*)&Qh[mi * 16 + l15][kk + koff];
            al[mi] = *(const short8*)&Ql[mi * 16 + l15][kk + koff];
        }
        #pragma unroll
        for (int ni = 0; ni < FN; ++ni) {
            long krow = wid * WCOLS + ni * 16 + l15;
            short8 bh = *(const short8*)(kh + krow * LDQK + kk + koff);
            short8 bl = *(const short8*)(kl + krow * LDQK + kk + koff);
            #pragma unroll
            for (int mi = 0; mi < 2; ++mi) {
                acc[mi][ni] = __builtin_amdgcn_mfma_f32_16x16x32_bf16(al[mi], bh, acc[mi][ni], 0, 0, 0);
                acc[mi][ni] = __builtin_amdgcn_mfma_f32_16x16x32_bf16(ah[mi], bl, acc[mi][ni], 0, 0, 0);
                acc[mi][ni] = __builtin_amdgcn_mfma_f32_16x16x32_bf16(ah[mi], bh, acc[mi][ni], 0, 0, 0);
            }
        }
    }

    float pm[2][4];
    #pragma unroll
    for (int mi = 0; mi < 2; ++mi)
        #pragma unroll
        for (int j = 0; j < 4; ++j) {
            float m = acc[mi][0][j];
            #pragma unroll
            for (int ni = 1; ni < FN; ++ni) m = fmaxf(m, acc[mi][ni][j]);
            pm[mi][j] = m;
        }
    #pragma unroll
    for (int msk = 1; msk < 16; msk <<= 1) {
        #pragma unroll
        for (int mi = 0; mi < 2; ++mi)
            #pragma unroll
            for (int j = 0; j < 4; ++j)
                pm[mi][j] = fmaxf(pm[mi][j], __shfl_xor(pm[mi][j], msk));
    }
    if (l15 == 0) {
        #pragma unroll
        for (int mi = 0; mi < 2; ++mi)
            #pragma unroll
            for (int j = 0; j < 4; ++j) red[mi * 16 + g * 4 + j][wid] = pm[mi][j];
    }
    __syncthreads();
    float rm[2][4];
    #pragma unroll
    for (int mi = 0; mi < 2; ++mi)
        #pragma unroll
        for (int j = 0; j < 4; ++j) {
            const float* r4 = red[mi * 16 + g * 4 + j];
            rm[mi][j] = fmaxf(fmaxf(r4[0], r4[1]), fmaxf(r4[2], r4[3]));
        }
    __syncthreads();

    float ps[2][4] = {};
    #pragma unroll
    for (int mi = 0; mi < 2; ++mi)
        #pragma unroll
        for (int ni = 0; ni < FN; ++ni)
            #pragma unroll
            for (int j = 0; j < 4; ++j) {
                float e = __expf(acc[mi][ni][j] - rm[mi][j]);
                acc[mi][ni][j] = e;
                ps[mi][j] += e;
            }
    #pragma unroll
    for (int msk = 1; msk < 16; msk <<= 1) {
        #pragma unroll
        for (int mi = 0; mi < 2; ++mi)
            #pragma unroll
            for (int j = 0; j < 4; ++j)
                ps[mi][j] += __shfl_xor(ps[mi][j], msk);
    }
    if (l15 == 0) {
        #pragma unroll
        for (int mi = 0; mi < 2; ++mi)
            #pragma unroll
            for (int j = 0; j < 4; ++j) red[mi * 16 + g * 4 + j][wid] = ps[mi][j];
    }
    __syncthreads();
    float inv[2][4];
    #pragma unroll
    for (int mi = 0; mi < 2; ++mi)
        #pragma unroll
        for (int j = 0; j < 4; ++j) {
            const float* r4 = red[mi * 16 + g * 4 + j];
            inv[mi][j] = 1.0f / (r4[0] + r4[1] + r4[2] + r4[3]);
        }

    #pragma unroll
    for (int mi = 0; mi < 2; ++mi)
        #pragma unroll
        for (int ni = 0; ni < FN; ++ni)
            #pragma unroll
            for (int j = 0; j < 4; ++j)
                Pl[mi * 16 + g * 4 + j][wid * WCOLS + ni * 16 + l15] =
                    (unsigned short)bf16_rne(acc[mi][ni][j] * inv[mi][j]);
    __syncthreads();

    constexpr int PCH = COLS / 8;
    for (int i = tid; i < 32 * PCH; i += 256) {
        int r = i / PCH, c = (i % PCH) * 8;
        *(ushortx8*)(P + (rowBase + q0 + r) * COLS + c) = *(const ushortx8*)&Pl[r][c];
    }
}

// ---------------------------------------------------------------------------
// Transpose + split: in[R][C] fp32 -> outH/outL[(c+rowOff)][r] bf16 planes
// ---------------------------------------------------------------------------
__global__ __launch_bounds__(256)
void transpose_split(const float* __restrict__ in,
                     unsigned short* __restrict__ outH,
                     unsigned short* __restrict__ outL,
                     int R, int C, int rowOff, int ldo)
{
    __shared__ float tile[32][33];
    const int tc = blockIdx.x * 32, tr = blockIdx.y * 32;
    const int x = threadIdx.x, y = threadIdx.y;
    #pragma unroll
    for (int i = 0; i < 32; i += 8)
        tile[y + i][x] = in[(long)(tr + y + i) * C + tc + x];
    __syncthreads();
    #pragma unroll
    for (int i = 0; i < 32; i += 8) {
        float v = tile[x][y + i];
        unsigned int h = bf16_rne(v);
        float hf = __uint_as_float(h << 16);
        unsigned int lo = bf16_rne(v - hf);
        long idx = (long)(tc + y + i + rowOff) * ldo + tr + x;
        outH[idx] = (unsigned short)h;
        outL[idx] = (unsigned short)lo;
    }
}

extern "C" void kernel_launch(void* const* d_in, const int* in_sizes, int n_in,
                              void* d_out, int out_size, void* d_ws, size_t ws_size,
                              hipStream_t stream)
{
    (void)in_sizes; (void)n_in; (void)out_size; (void)ws_size;
    const float* x_T    = (const float*)d_in[0];
    const float* x_S    = (const float*)d_in[1];
    const float* Wq_T   = (const float*)d_in[2];
    const float* Wk_T   = (const float*)d_in[3];
    const float* Wv_T   = (const float*)d_in[4];
    const float* Wq_S   = (const float*)d_in[5];
    const float* Wk_S   = (const float*)d_in[6];
    const float* Wout_T = (const float*)d_in[7];
    const float* bout_T = (const float*)d_in[8];
    const float* bias_T = (const float*)d_in[9];
    const float* bias_S = (const float*)d_in[10];
    float* out = (float*)d_out;

    constexpr int B = 16, T = 1024, N = 512, DKT = 64, DKS = 128;
    typedef unsigned short us;

    char* w = (char*)d_ws;
    size_t off = 0;
    auto alloc = [&](size_t bytes) { char* p = w + off; off = (off + bytes + 255) & ~(size_t)255; return p; };
    us* wqkT_h = (us*)alloc(128 * 512 * 2);
    us* wqkT_l = (us*)alloc(128 * 512 * 2);
    us* wvt_h  = (us*)alloc(512 * 512 * 2);
    us* wvt_l  = (us*)alloc(512 * 512 * 2);
    us* wqks_h = (us*)alloc(256 * 1024 * 2);
    us* wqks_l = (us*)alloc(256 * 1024 * 2);
    us* wout_h = (us*)alloc(512 * 512 * 2);
    us* wout_l = (us*)alloc(512 * 512 * 2);
    us* qk_h   = (us*)alloc((size_t)16384 * 128 * 2);  // temporal q|k; spatial [8192][256]
    us* qk_l   = (us*)alloc((size_t)16384 * 128 * 2);
    us* P_T    = (us*)alloc((size_t)B * T * T * 2);    // 32 MB
    us* P_S    = (us*)alloc((size_t)B * N * N * 2);    // 8 MB
    us* vT_h   = (us*)alloc((size_t)B * N * T * 2);    // v^T hi; reused as out2_h
    us* vT_l   = (us*)alloc((size_t)B * N * T * 2);    // reused as out2_l
    us* outT_h = (us*)alloc((size_t)B * T * N * 2);
    us* outT_l = (us*)alloc((size_t)B * T * N * 2);
    us* out2_h = vT_h;
    us* out2_l = vT_l;

    const float scale_T = 0.125f;
    const float scale_S = 0.088388347648318447f;
    const int BIG = 1 << 30;

    dim3 tb(32, 8);
    transpose_split<<<dim3(2, 16),  tb, 0, stream>>>(Wq_T,   wqkT_h, wqkT_l, 512, 64,   0, 512);
    transpose_split<<<dim3(2, 16),  tb, 0, stream>>>(Wk_T,   wqkT_h, wqkT_l, 512, 64,  64, 512);
    transpose_split<<<dim3(16, 16), tb, 0, stream>>>(Wv_T,   wvt_h,  wvt_l,  512, 512,  0, 512);
    transpose_split<<<dim3(4, 32),  tb, 0, stream>>>(Wq_S,   wqks_h, wqks_l, 1024, 128, 0, 1024);
    transpose_split<<<dim3(4, 32),  tb, 0, stream>>>(Wk_S,   wqks_h, wqks_l, 1024, 128, 128, 1024);
    transpose_split<<<dim3(16, 16), tb, 0, stream>>>(Wout_T, wout_h, wout_l, 512, 512,  0, 512);

    // ---- temporal chain ----
    // qk = x_T @ [Wq|Wk]^T (cols<64: *scale_T + bias_T)  [16384 x 128], K=512, 3-pass
    // BM=32,BN=128: x_T fetched exactly once, 512 blocks
    gemm_nt<32, 128, 1, 3, 2, true><<<dim3(1, 512, 1), 256, 0, stream>>>(
        x_T, nullptr, wqkT_h, wqkT_l, qk_h, qk_l, bias_T,
        512, 512, 512, 128, 0, 0, 0, scale_T, 64);
    // v^T_b = Wv^T @ x_b^T  [512 x 1024] per b, K=512, 2-pass, hi-only out
    gemm_nt<128, 128, 3, 0, 3, false><<<dim3(8, 4, B), 256, 0, stream>>>(
        wvt_h, wvt_l, x_T, nullptr, vT_h, nullptr, nullptr,
        512, 512, 512, 1024, 0, (long)T * N, (long)N * T, 1.0f, 0);
    // fused logits_T + softmax -> P_T bf16  [per b: 1024 x 1024]
    qk_softmax<1024, 64, 128><<<dim3(32, 16), 256, 0, stream>>>(qk_h, qk_l, P_T);
    // outT = P_T @ v  (NT vs v^T)  [1024 x 512] per b, K=1024, 1-pass (P-hi x v-hi)
    gemm_nt<128, 128, 2, 2, 2, false><<<dim3(4, 8, B), 256, 0, stream>>>(
        P_T, nullptr, vT_h, nullptr, outT_h, outT_l, nullptr,
        1024, 1024, 1024, 512, (long)T * T, (long)N * T, (long)T * N, 1.0f, 0);

    // ---- spatial chain ----
    // qkS = x_S @ [WqS|WkS]^T (cols<128: *scale_S + bias_S)  [8192 x 256], K=1024, 3-pass
    // BM=32,BN=128: col-tile pairs share x_S rows -> same XCD via swizzle
    gemm_nt<32, 128, 1, 3, 2, true><<<dim3(2, 256, 1), 256, 0, stream>>>(
        x_S, nullptr, wqks_h, wqks_l, qk_h, qk_l, bias_S,
        1024, 1024, 1024, 256, 0, 0, 0, scale_S, 128);
    // fused logits_S + softmax -> P_S bf16  [per b: 512 x 512]
    qk_softmax<512, 128, 256><<<dim3(16, 16), 256, 0, stream>>>(qk_h, qk_l, P_S);
    // out2 = outT_b @ P_S_b^T  [1024 x 512] per b, K=512, 2-pass
    gemm_nt<128, 128, 3, 2, 2, false><<<dim3(4, 8, B), 256, 0, stream>>>(
        outT_h, outT_l, P_S, nullptr, out2_h, out2_l, nullptr,
        512, 512, 512, 512, (long)T * N, (long)N * N, (long)T * N, 1.0f, 0);
    // out[b,i,t] = (out2_b @ Wout + bout)^T  [512 x 1024] per b, K=512, 2-pass
    gemm_nt<128, 128, 3, 2, 1, true><<<dim3(4, 8, B), 256, 0, stream>>>(
        out2_h, out2_l, wout_h, nullptr, out, nullptr, bout_T,
        512, 512, 512, 1024, (long)T * N, 0, (long)N * T, 1.0f, BIG);
}